// Round 3
// baseline (434.676 us; speedup 1.0000x reference)
//
#include <hip/hip_runtime.h>
#include <cstdint>
#include <cstddef>

#define DEV static __device__ __forceinline__

typedef __attribute__((ext_vector_type(8))) short bf16x8_t;
typedef __attribute__((ext_vector_type(4))) float f32x4_t;

DEV unsigned short f2bf(float f) {
  union { float f; unsigned u; } v; v.f = f;
  unsigned r = v.u + 0x7fffu + ((v.u >> 16) & 1u);
  return (unsigned short)(r >> 16);
}

// async global->LDS, 16B per lane; LDS dest = wave-uniform base + lane*16
DEV void gl_lds16(const void* g, void* l) {
  __builtin_amdgcn_global_load_lds(
      (const __attribute__((address_space(1))) void*)g,
      (__attribute__((address_space(3))) void*)l,
      16, 0, 0);
}

// ---------------- prep: build_idx + casts + transposes, one launch --------
__global__ __launch_bounds__(256)
void prep_k(const int* __restrict__ target,
            int* __restrict__ idx1, int* __restrict__ pos1,
            int* __restrict__ idx2, int* __restrict__ pos2,
            int* __restrict__ cnts,
            const float* __restrict__ p0, const float* __restrict__ p1,
            const float* __restrict__ p2, unsigned short* __restrict__ pAll,
            const float* __restrict__ s0, unsigned short* __restrict__ d0, int n0,
            const float* __restrict__ s1, unsigned short* __restrict__ d1, int n1,
            const float* __restrict__ s2, unsigned short* __restrict__ d2, int n2,
            const float* __restrict__ s3, unsigned short* __restrict__ d3, int n3,
            const float* __restrict__ s4, unsigned short* __restrict__ d4, int n4) {
  const int bid = blockIdx.x;
  const int tid = threadIdx.x;
  if (bid == 0) {
    __shared__ int c1, c2;
    if (tid == 0) { c1 = 0; c2 = 0; }
    __syncthreads();
    for (int i = tid; i < 2048; i += 256) {
      int t = target[i];
      if (t >= 20000 && t < 50000) {
        int p = atomicAdd(&c1, 1); idx1[p] = i; pos1[i] = p;
      } else if (t >= 50000) {
        int p = atomicAdd(&c2, 1); idx2[p] = i; pos2[i] = p;
      }
    }
    __syncthreads();
    if (tid == 0) { cnts[0] = c1; cnts[1] = c2; cnts[2] = 256; }
    return;
  }
  if (bid <= 1344) {
    __shared__ float tile[32][33];
    int b = bid - 1;
    const float* src; unsigned short* dst; int C, bx, by;
    if (b < 1024)      { src = p0; dst = pAll;               C = 1024; bx = b % 32; by = b / 32; }
    else if (b < 1280) { int q = b - 1024; src = p1; dst = pAll + 1024 * 1024; C = 256; bx = q % 8; by = q / 8; }
    else               { int q = b - 1280; src = p2; dst = pAll + 1280 * 1024; C = 64;  bx = q % 2; by = q / 2; }
    const int R = 1024;
    int tx = tid & 31, ty = tid >> 5;
    int c0 = bx * 32, r0 = by * 32;
    for (int yy = ty; yy < 32; yy += 8)
      tile[yy][tx] = src[(size_t)(r0 + yy) * C + (c0 + tx)];
    __syncthreads();
    for (int yy = ty; yy < 32; yy += 8)
      dst[(size_t)(c0 + yy) * R + (r0 + tx)] = f2bf(tile[tx][yy]);
    return;
  }
  int j = (bid - 1345) * 256 + tid;
  const float* s; unsigned short* d;
  if (j < n0) { s = s0; d = d0; }
  else { j -= n0;
    if (j < n1) { s = s1; d = d1; }
    else { j -= n1;
      if (j < n2) { s = s2; d = d2; }
      else { j -= n2;
        if (j < n3) { s = s3; d = d3; }
        else { j -= n3; if (j >= n4) return; s = s4; d = d4; }
      }
    }
  }
  float4 f = ((const float4*)s)[j];
  ushort4 o;
  o.x = f2bf(f.x); o.y = f2bf(f.y); o.z = f2bf(f.z); o.w = f2bf(f.w);
  ((ushort4*)d)[j] = o;
}

// ---------------- proj GEMM: Pall[2048,1344] = Hb @ pAll^T ----------------
__global__ __launch_bounds__(256)
void proj_gemm_k(const unsigned short* __restrict__ A,
                 const unsigned short* __restrict__ W,
                 unsigned short* __restrict__ Cout) {
  __shared__ __align__(16) unsigned short As[128 * 32];
  __shared__ __align__(16) unsigned short Bs[128 * 32];
  const int K = 1024, V = 1344;
  const int tm = blockIdx.x, tn = blockIdx.y;
  const int m0 = tm * 128, n0 = tn * 128;
  const int tid = threadIdx.x, wid = tid >> 6, lane = tid & 63;
  const int quad = lane >> 4, l16 = lane & 15;
  const int wr = wid >> 1, wc = wid & 1;

  f32x4_t acc[4][4];
  const f32x4_t zero4 = {0.f, 0.f, 0.f, 0.f};
#pragma unroll
  for (int i = 0; i < 4; ++i)
#pragma unroll
    for (int j = 0; j < 4; ++j) acc[i][j] = zero4;

  const int srow = wid * 32 + (lane >> 2);
  const int skk  = (lane & 3) * 8;
  const unsigned short* Ap0 = A + (size_t)(m0 + srow) * K + skk;
  const unsigned short* Ap1 = A + (size_t)(m0 + srow + 16) * K + skk;
  int wrow0 = n0 + srow;      if (wrow0 > V - 1) wrow0 = V - 1;
  int wrow1 = n0 + srow + 16; if (wrow1 > V - 1) wrow1 = V - 1;
  const unsigned short* Wp0 = W + (size_t)wrow0 * K + skk;
  const unsigned short* Wp1 = W + (size_t)wrow1 * K + skk;
  unsigned short* Asw = As + wid * 1024;
  unsigned short* Bsw = Bs + wid * 1024;

  for (int k0 = 0; k0 < K; k0 += 32) {
    gl_lds16(Ap0, Asw);
    gl_lds16(Ap1, Asw + 512);
    gl_lds16(Wp0, Bsw);
    gl_lds16(Wp1, Bsw + 512);
    Ap0 += 32; Ap1 += 32; Wp0 += 32; Wp1 += 32;
    __syncthreads();
    bf16x8_t af[4], bfr[4];
#pragma unroll
    for (int i = 0; i < 4; ++i)
      af[i] = *(const bf16x8_t*)(As + (size_t)(wr * 64 + i * 16 + l16) * 32 + quad * 8);
#pragma unroll
    for (int j = 0; j < 4; ++j)
      bfr[j] = *(const bf16x8_t*)(Bs + (size_t)(wc * 64 + j * 16 + l16) * 32 + quad * 8);
#pragma unroll
    for (int i = 0; i < 4; ++i)
#pragma unroll
      for (int j = 0; j < 4; ++j)
        acc[i][j] = __builtin_amdgcn_mfma_f32_16x16x32_bf16(af[i], bfr[j], acc[i][j], 0, 0, 0);
    __syncthreads();
  }
#pragma unroll
  for (int i = 0; i < 4; ++i)
#pragma unroll
    for (int j = 0; j < 4; ++j) {
      const int n = n0 + wc * 64 + j * 16 + l16;
      if (n < V) {
#pragma unroll
        for (int r = 0; r < 4; ++r) {
          const int m = m0 + wr * 64 + i * 16 + quad * 4 + r;
          Cout[(size_t)m * V + n] = f2bf(acc[i][j][r]);
        }
      }
    }
}

// ---------------- head GEMM: persistent 256x256 8-phase, de-pinned --------
// Changes vs R2 (theory: m141 order-pinning regression + grid quantization):
// 1. NO sched_barrier(0) anywhere; exact m201 phase shape
//    {reads; stage; s_barrier; lgkmcnt(0)-fence; setprio MFMA setprio;
//    s_barrier}, 8 barriers/K-tile. asm "memory" fences at waitcnts are the
//    only compiler fences (they bound ds_read hoisting and keep the staged
//    LDS write-after-read protocol: every region is re-staged only after a
//    barrier all waves reached past the lgkm fence completing its reads).
// 2. Persistent blocks: grid=256, tiles (632 = 8 mt x 79 stripes) popped
//    from a device atomic (identity order: consecutive pops = 8 m-tiles of
//    one stripe -> W-stripe shared in the active window). Tile boundary:
//    pop -> vmcnt(0) drain -> issue next tile's 6-stage prologue -> current
//    epilogue (separate redf2, lgkm-fence + raw barrier so prologue stays
//    in flight) -> vmcnt(4). Removes round quantization + hides prologue.
// Full-rank LDS swizzle (R2, conflicts==0) unchanged.

#define SBAR() __builtin_amdgcn_s_barrier()
#define LGKM0() asm volatile("s_waitcnt lgkmcnt(0)" ::: "memory")

#define STA(BUF, HALF, KT)                                                    \
  {                                                                           \
    const unsigned short* g_ = aB0 + (size_t)(HALF) * (128 * 1344) + (KT) * 64; \
    char* d_ = (char*)SA[BUF][HALF] + ldsw;                                   \
    gl_lds16(g_, d_);                                                         \
    gl_lds16(g_ + 64 * 1344, d_ + 8192);                                      \
  }

#define STB(BUF, HALF, KT)                                                    \
  {                                                                           \
    char* d_ = (char*)SB[BUF][HALF] + ldsw;                                   \
    gl_lds16(bP##HALF##0 + (KT) * 64, d_);                                    \
    gl_lds16(bP##HALF##1 + (KT) * 64, d_ + 8192);                             \
  }

#define MM16(mb, nb)                                                          \
  {                                                                           \
    _Pragma("unroll") for (int mi = 0; mi < 4; ++mi) {                        \
      _Pragma("unroll") for (int nj = 0; nj < 2; ++nj) {                      \
        acc[(mb) + mi][(nb) + nj] = __builtin_amdgcn_mfma_f32_16x16x32_bf16(  \
            Af[0][mi], Bf[(nb) / 2][0][nj], acc[(mb) + mi][(nb) + nj], 0, 0, 0); \
        acc[(mb) + mi][(nb) + nj] = __builtin_amdgcn_mfma_f32_16x16x32_bf16(  \
            Af[1][mi], Bf[(nb) / 2][1][nj], acc[(mb) + mi][(nb) + nj], 0, 0, 0); \
      }                                                                       \
    }                                                                         \
  }

#define PH(D_, E_, KTV)                                                       \
  {                                                                           \
    const int kt_ = (KTV);                                                    \
    const int t1_ = (kt_ + 1 > 15) ? 15 : (kt_ + 1);                          \
    const int t2_ = (kt_ + 2 > 15) ? 15 : (kt_ + 2);                          \
    /* q0: Af-lo + Bf-lo; stage B1(kt+1) */                                   \
    _Pragma("unroll") for (int mi = 0; mi < 4; ++mi) {                        \
      Af[0][mi] = *(const bf16x8_t*)(pa##D_##a + mi * 2048);                  \
      Af[1][mi] = *(const bf16x8_t*)(pa##D_##b + mi * 2048);                  \
    }                                                                         \
    _Pragma("unroll") for (int nj = 0; nj < 2; ++nj) {                        \
      Bf[0][0][nj] = *(const bf16x8_t*)(pb##D_##a + nj * 2048);               \
      Bf[0][1][nj] = *(const bf16x8_t*)(pb##D_##b + nj * 2048);               \
    }                                                                         \
    STB(E_, 1, t1_);                                                          \
    SBAR(); LGKM0();                                                          \
    __builtin_amdgcn_s_setprio(1); MM16(0, 0); __builtin_amdgcn_s_setprio(0); \
    SBAR();                                                                   \
    /* q1: Bf-hi; stage A1(kt+1) */                                           \
    _Pragma("unroll") for (int nj = 0; nj < 2; ++nj) {                        \
      Bf[1][0][nj] = *(const bf16x8_t*)(pb##D_##a + (2 + nj) * 2048);         \
      Bf[1][1][nj] = *(const bf16x8_t*)(pb##D_##b + (2 + nj) * 2048);         \
    }                                                                         \
    STA(E_, 1, t1_);                                                          \
    SBAR(); LGKM0();                                                          \
    __builtin_amdgcn_s_setprio(1); MM16(0, 2); __builtin_amdgcn_s_setprio(0); \
    SBAR();                                                                   \
    /* q2: Af-hi; stage B0(kt+2) */                                           \
    _Pragma("unroll") for (int mi = 0; mi < 4; ++mi) {                        \
      Af[0][mi] = *(const bf16x8_t*)(pa##D_##a + (4 + mi) * 2048);            \
      Af[1][mi] = *(const bf16x8_t*)(pa##D_##b + (4 + mi) * 2048);            \
    }                                                                         \
    STB(D_, 0, t2_);                                                          \
    SBAR(); LGKM0();                                                          \
    __builtin_amdgcn_s_setprio(1); MM16(4, 0); __builtin_amdgcn_s_setprio(0); \
    SBAR();                                                                   \
    /* q3: stage A0(kt+2); counted vmcnt(4) once per K-tile */                \
    STA(D_, 0, t2_);                                                          \
    SBAR();                                                                   \
    __builtin_amdgcn_s_setprio(1); MM16(4, 2); __builtin_amdgcn_s_setprio(0); \
    asm volatile("s_waitcnt vmcnt(4)" ::: "memory");                          \
    SBAR();                                                                   \
  }

#define PROLOGUE6()                                                           \
  { STB(0, 0, 0); STA(0, 0, 0); STB(0, 1, 0); STA(0, 1, 0);                   \
    STB(1, 0, 1); STA(1, 0, 1); }

__global__ __launch_bounds__(512, 2)
void head256_k(const unsigned short* __restrict__ Pall,
               const unsigned short* __restrict__ w0b,
               const float* __restrict__ b0, const float* __restrict__ cb,
               float* __restrict__ part0, float* __restrict__ g0,
               float* __restrict__ cg, const int* __restrict__ target,
               int* __restrict__ tilectr) {
  __shared__ __align__(16) unsigned short SA[2][2][8192];  // [dbuf][half][128*64]
  __shared__ __align__(16) unsigned short SB[2][2][8192];
  __shared__ float redf2[1024];
  __shared__ int nextS;

  const int V = 20002, NTILE = 632;
  const int tid = threadIdx.x;
  const int wid = tid >> 6, lane = tid & 63;
  const int quad = lane >> 4, l16 = lane & 15;
  const int wr = wid >> 2, wc = wid & 3;

  // staging source decode (full-rank swizzle inverse): thread fills phys
  // bytes {tid*16, 8192+tid*16}; phys row tid>>3, phys slot tid&7 ->
  // logical col16 = slot ^ (row&7).
  const int r0  = tid >> 3;                       // phys row 0..63
  const int ibh = ((tid & 7) ^ (r0 & 7)) << 3;    // logical element col
  const int ldsw = wid * 1024;                    // wave-uniform gl_lds base

  // swizzled ds_read lane offsets: slot = (quad+4kk) ^ (l16&7)
  const int aoff0 = l16 * 128 + ((quad ^ (l16 & 3)) << 4) + (((l16 >> 2) & 1) << 6);
  const int aoff1 = aoff0 ^ 64;
  const char* pa0a = (const char*)SA[0][wr] + aoff0;
  const char* pa0b = (const char*)SA[0][wr] + aoff1;
  const char* pa1a = (const char*)SA[1][wr] + aoff0;
  const char* pa1b = (const char*)SA[1][wr] + aoff1;
  const char* pb0a = (const char*)SB[0][wc >> 1] + (wc & 1) * 8192 + aoff0;
  const char* pb0b = (const char*)SB[0][wc >> 1] + (wc & 1) * 8192 + aoff1;
  const char* pb1a = (const char*)SB[1][wc >> 1] + (wc & 1) * 8192 + aoff0;
  const char* pb1b = (const char*)SB[1][wc >> 1] + (wc & 1) * 8192 + aoff1;

  // per-tile mutable state
  int m0, n0, stripe;
  const unsigned short* aB0;
  const unsigned short *bP00, *bP01, *bP10, *bP11;

  int tile = blockIdx.x;  // static first assignment; ctr starts at 256
#define DECODE(T)                                                             \
  {                                                                           \
    const int t_ = (T);                                                       \
    stripe = t_ >> 3; m0 = (t_ & 7) * 256; n0 = stripe * 256;                 \
    aB0 = Pall + (size_t)(m0 + r0) * 1344 + ibh;                              \
    int q00 = n0 + r0;            if (q00 > V - 1) q00 = V - 1;               \
    int q01 = n0 + r0 + 64;       if (q01 > V - 1) q01 = V - 1;               \
    int q10 = n0 + 128 + r0;      if (q10 > V - 1) q10 = V - 1;               \
    int q11 = n0 + 128 + r0 + 64; if (q11 > V - 1) q11 = V - 1;               \
    bP00 = w0b + (size_t)q00 * 1024 + ibh;                                    \
    bP01 = w0b + (size_t)q01 * 1024 + ibh;                                    \
    bP10 = w0b + (size_t)q10 * 1024 + ibh;                                    \
    bP11 = w0b + (size_t)q11 * 1024 + ibh;                                    \
  }

  DECODE(tile);
  PROLOGUE6();
  asm volatile("s_waitcnt vmcnt(4)" ::: "memory");
  SBAR();

  f32x4_t acc[8][4];
  bf16x8_t Af[2][4];
  bf16x8_t Bf[2][2][2];
  const f32x4_t zero4 = {0.f, 0.f, 0.f, 0.f};

  while (true) {
#pragma unroll
    for (int i = 0; i < 8; ++i)
#pragma unroll
      for (int j = 0; j < 4; ++j) acc[i][j] = zero4;

#pragma unroll 1
    for (int ktp = 0; ktp < 8; ++ktp) {
      const int kt0 = 2 * ktp;
      PH(0, 1, kt0);
      PH(1, 0, kt0 + 1);
    }

    // pop next tile; drain dup-stage writes before any re-staging
    if (tid == 0) nextS = atomicAdd(tilectr, 1);
    asm volatile("s_waitcnt vmcnt(0) lgkmcnt(0)" ::: "memory");
    SBAR();
    const int next = nextS;
    const bool more = (next < NTILE);

    // capture current tile's epilogue params BEFORE re-decoding
    const int em0 = m0, estripe = stripe;
    int nj[4]; float bj[4];
#pragma unroll
    for (int j = 0; j < 4; ++j) {
      nj[j] = n0 + wc * 64 + j * 16 + l16;
      bj[j] = (nj[j] < 20000) ? b0[nj[j]] : ((nj[j] < V) ? cb[nj[j] - 20000] : 0.f);
    }

    if (more) {
      DECODE(next);
      PROLOGUE6();  // next tile's kt0+kt1 stages fly under the epilogue
    }

    // epilogue (redf2 separate from staging buffers)
#pragma unroll
    for (int i = 0; i < 8; ++i) {
#pragma unroll
      for (int r = 0; r < 4; ++r) {
        const int rloc = i * 16 + quad * 4 + r;
        const int token = em0 + wr * 128 + rloc;
        float v[4], sum = 0.f;
#pragma unroll
        for (int j = 0; j < 4; ++j) {
          v[j] = acc[i][j][r] + bj[j];
          if (nj[j] < V) sum += __expf(v[j]);
        }
#pragma unroll
        for (int off = 1; off < 16; off <<= 1)
          sum += __shfl_xor(sum, off, 64);
        if (l16 == 0) redf2[(wr * 4 + wc) * 128 + rloc] = sum;
        const int t = target[token];
        const int gi = (t < 19999) ? t : 19999;
#pragma unroll
        for (int j = 0; j < 4; ++j) {
          if (nj[j] == gi) g0[token] = v[j];
          if (nj[j] == 20000) cg[2 * token]     = v[j];
          if (nj[j] == 20001) cg[2 * token + 1] = v[j];
        }
      }
    }
    LGKM0();   // redf2 ds_writes done (no vmcnt drain: prologue stays in flight)
    SBAR();
    if (tid < 256) {
      const int wrr = tid >> 7, rr = tid & 127;
      const float s = redf2[(wrr * 4 + 0) * 128 + rr] + redf2[(wrr * 4 + 1) * 128 + rr]
                    + redf2[(wrr * 4 + 2) * 128 + rr] + redf2[(wrr * 4 + 3) * 128 + rr];
      part0[(size_t)(em0 + tid) * 79 + estripe] = s;
    }
    if (!more) return;

    // prologue landed (stores may linger as the newest 4)
    asm volatile("s_waitcnt vmcnt(4)" ::: "memory");
    SBAR();
    tile = next;
  }
#undef DECODE
}

#undef PH
#undef MM16
#undef STA
#undef STB
#undef PROLOGUE6
#undef SBAR
#undef LGKM0

// ---------------- stripe-persistent tail GEMM -----------------------------
template <int KT>
__global__ __launch_bounds__(256, 1)
void tail_stripe_k(const unsigned short* __restrict__ A, int ldA,
                   const unsigned short* __restrict__ W,
                   const float* __restrict__ bias, int V, int ntiles,
                   const int* __restrict__ rowidx,
                   const int* __restrict__ cnt_ptr,
                   float* __restrict__ partials,
                   float* __restrict__ gathered,
                   const int* __restrict__ target, int glo) {
  constexpr int NC = KT / 32;
  __shared__ __align__(16) unsigned short Ws[NC][128 * 32];
  __shared__ __align__(16) unsigned short As[NC][128 * 32];
  __shared__ float red[2][128];

  const int tn = blockIdx.x, n0 = tn * 128;
  const int Meff = *cnt_ptr;
  const int tid = threadIdx.x, wid = tid >> 6, lane = tid & 63;
  const int quad = lane >> 4, l16 = lane & 15;
  const int wr = wid >> 1, wc = wid & 1;
  const int srow = wid * 32 + (lane >> 2);
  const int skk  = (lane & 3) * 8;

  int wrow0 = n0 + srow;      if (wrow0 > V - 1) wrow0 = V - 1;
  int wrow1 = n0 + srow + 16; if (wrow1 > V - 1) wrow1 = V - 1;
#pragma unroll
  for (int c = 0; c < NC; ++c) {
    gl_lds16(W + (size_t)wrow0 * KT + c * 32 + skk, Ws[c] + wid * 1024);
    gl_lds16(W + (size_t)wrow1 * KT + c * 32 + skk, Ws[c] + wid * 1024 + 512);
  }

  int nj[4]; float bj[4];
#pragma unroll
  for (int j = 0; j < 4; ++j) {
    nj[j] = n0 + wc * 64 + j * 16 + l16;
    bj[j] = (nj[j] < V) ? bias[nj[j]] : 0.f;
  }

  const int nm = (Meff + 127) >> 7;
  for (int m = 0; m < nm; ++m) {
    const int m0 = m * 128;
    int ar0 = m0 + srow;      if (ar0 > Meff - 1) ar0 = Meff - 1;
    int ar1 = m0 + srow + 16; if (ar1 > Meff - 1) ar1 = Meff - 1;
    ar0 = rowidx[ar0]; ar1 = rowidx[ar1];
#pragma unroll
    for (int c = 0; c < NC; ++c) {
      gl_lds16(A + (size_t)ar0 * ldA + c * 32 + skk, As[c] + wid * 1024);
      gl_lds16(A + (size_t)ar1 * ldA + c * 32 + skk, As[c] + wid * 1024 + 512);
    }
    __syncthreads();

    f32x4_t acc[4][4];
    const f32x4_t zero4 = {0.f, 0.f, 0.f, 0.f};
#pragma unroll
    for (int i = 0; i < 4; ++i)
#pragma unroll
      for (int j = 0; j < 4; ++j) acc[i][j] = zero4;
#pragma unroll
    for (int c = 0; c < NC; ++c) {
      bf16x8_t af[4], bfr[4];
#pragma unroll
      for (int i = 0; i < 4; ++i)
        af[i] = *(const bf16x8_t*)(As[c] + (size_t)(wr * 64 + i * 16 + l16) * 32 + quad * 8);
#pragma unroll
      for (int j = 0; j < 4; ++j)
        bfr[j] = *(const bf16x8_t*)(Ws[c] + (size_t)(wc * 64 + j * 16 + l16) * 32 + quad * 8);
#pragma unroll
      for (int i = 0; i < 4; ++i)
#pragma unroll
        for (int j = 0; j < 4; ++j)
          acc[i][j] = __builtin_amdgcn_mfma_f32_16x16x32_bf16(af[i], bfr[j], acc[i][j], 0, 0, 0);
    }

#pragma unroll
    for (int i = 0; i < 4; ++i) {
#pragma unroll
      for (int r = 0; r < 4; ++r) {
        const int row = wr * 64 + i * 16 + quad * 4 + r;
        const int gr = m0 + row;
        const int grc = (gr < Meff) ? gr : (Meff - 1);
        const int token = rowidx[grc];
        float v[4], sum = 0.f;
#pragma unroll
        for (int j = 0; j < 4; ++j) {
          v[j] = acc[i][j][r] + bj[j];
          if (nj[j] < V) sum += __expf(v[j]);
        }
#pragma unroll
        for (int off = 1; off < 16; off <<= 1)
          sum += __shfl_xor(sum, off, 64);
        if (l16 == 0) red[wc][row] = sum;
        const int gi = target[token] - glo;
#pragma unroll
        for (int j = 0; j < 4; ++j)
          if (nj[j] == gi) gathered[token] = v[j];
      }
    }
    __syncthreads();
    if (tid < 128 && (m0 + tid) < Meff)
      partials[(size_t)(m0 + tid) * ntiles + tn] = red[0][tid] + red[1][tid];
  }
}

// ---------------- combine: wave per token ----------------
__global__ __launch_bounds__(256)
void combine_k(const float* __restrict__ part0,
               const float* __restrict__ part1, int nt1,
               const float* __restrict__ part2, int nt2,
               const float* __restrict__ g0, const float* __restrict__ g1,
               const float* __restrict__ g2, const float* __restrict__ cg,
               const int* __restrict__ pos1, const int* __restrict__ pos2,
               const int* __restrict__ target, float* __restrict__ out) {
  const int w = threadIdx.x >> 6, lane = threadIdx.x & 63;
  const int token = blockIdx.x * 4 + w;
  const int t = target[token];

  float S = 0.f;
  for (int i = lane; i < 79; i += 64)
    S += part0[(size_t)token * 79 + i];
#pragma unroll
  for (int off = 1; off < 64; off <<= 1)
    S += __shfl_xor(S, off, 64);
  const float lse_head = __logf(S);

  float res;
  if (t < 20000) {
    res = lse_head - g0[token];
  } else {
    const float* pt; int nt; float gv, ch; int row;
    if (t < 50000) { pt = part1; nt = nt1; gv = g1[token]; ch = cg[2 * token + 1]; row = pos1[token]; }
    else           { pt = part2; nt = nt2; gv = g2[token]; ch = cg[2 * token];     row = pos2[token]; }
    float S2 = 0.f;
    for (int i = lane; i < nt; i += 64)
      S2 += pt[(size_t)row * nt + i];
#pragma unroll
    for (int off = 1; off < 64; off <<= 1)
      S2 += __shfl_xor(S2, off, 64);
    float lse_t = __logf(S2);
    res = -((ch - lse_head) + (gv - lse_t));
  }
  if (lane == 0) out[token] = res;
}

extern "C" void kernel_launch(void* const* d_in, const int* in_sizes, int n_in,
                              void* d_out, int out_size, void* d_ws, size_t ws_size,
                              hipStream_t stream) {
  (void)in_sizes; (void)n_in; (void)out_size; (void)ws_size;
  const float* hidden = (const float*)d_in[0];
  const int*   target = (const int*)d_in[1];
  const float* w0     = (const float*)d_in[2];
  const float* b0     = (const float*)d_in[3];
  const float* cw     = (const float*)d_in[4];
  const float* cb     = (const float*)d_in[5];
  const float* proj0  = (const float*)d_in[6];
  const float* w1     = (const float*)d_in[7];
  const float* b1     = (const float*)d_in[8];
  const float* proj1  = (const float*)d_in[9];
  const float* w2     = (const float*)d_in[10];
  const float* b2     = (const float*)d_in[11];
  const float* proj2  = (const float*)d_in[12];
  float* out = (float*)d_out;

  const int NT1 = 235, NT2 = 391;

  char* p = (char*)d_ws;
  auto alloc = [&](size_t bytes) {
    char* r = p; p += (bytes + 255) & ~(size_t)255; return r;
  };
  unsigned short* Hb   = (unsigned short*)alloc(2048ull * 1024 * 2);
  unsigned short* pAll = (unsigned short*)alloc(1344ull * 1024 * 2);
  unsigned short* w0b  = (unsigned short*)alloc(20002ull * 1024 * 2);
  unsigned short* w1b  = (unsigned short*)alloc(30000ull * 256 * 2);
  unsigned short* w2b  = (unsigned short*)alloc(50000ull * 64 * 2);
  unsigned short* Pall = (unsigned short*)alloc(2048ull * 1344 * 2);
  float* part0 = (float*)alloc(2048ull * 79 * 4);
  float* part1 = (float*)alloc(2048ull * NT1 * 4);
  float* part2 = (float*)alloc(2048ull * NT2 * 4);
  float* g0 = (float*)alloc(2048 * 4);
  float* g1 = (float*)alloc(2048 * 4);
  float* g2 = (float*)alloc(2048 * 4);
  float* cg = (float*)alloc(2048 * 2 * 4);
  int* idx1 = (int*)alloc(2048 * 4);
  int* pos1 = (int*)alloc(2048 * 4);
  int* idx2 = (int*)alloc(2048 * 4);
  int* pos2 = (int*)alloc(2048 * 4);
  int* cnts = (int*)alloc(4 * 4);   // [0]=c1 [1]=c2 [2]=head tile counter

  const int c_h = 2048 * 1024 / 4, c_w0 = 20000 * 1024 / 4, c_cw = 2048 / 4,
            c_w1 = 30000 * 256 / 4, c_w2 = 50000 * 64 / 4;
  const int ctot = c_h + c_w0 + c_cw + c_w1 + c_w2;
  const int nb_cast = (ctot + 255) / 256;
  prep_k<<<1 + 1344 + nb_cast, 256, 0, stream>>>(
      target, idx1, pos1, idx2, pos2, cnts,
      proj0, proj1, proj2, pAll,
      hidden, Hb, c_h,
      w0, w0b, c_w0,
      cw, w0b + 20000ull * 1024, c_cw,
      w1, w1b, c_w1,
      w2, w2b, c_w2);

  // merged projections: Pall[2048,1344] = Hb @ pAll^T
  proj_gemm_k<<<dim3(16, 11), 256, 0, stream>>>(Hb, pAll, Pall);

  // head: persistent 256^2 8-phase GEMM, 256 blocks pop 632 tiles
  head256_k<<<256, 512, 0, stream>>>(Pall, w0b, b0, cb, part0, g0, cg, target,
                                     cnts + 2);

  // tails: one block per stripe, W persistent in LDS, m-loop inside
  tail_stripe_k<256><<<NT1, 256, 0, stream>>>(
      Pall + 1024, 1344, w1b, b1, 30000, NT1, idx1, cnts + 0,
      part1, g1, target, 20000);
  tail_stripe_k<64><<<NT2, 256, 0, stream>>>(
      Pall + 1280, 1344, w2b, b2, 50000, NT2, idx2, cnts + 1,
      part2, g2, target, 50000);

  combine_k<<<512, 256, 0, stream>>>(part0, part1, NT1, part2, NT2,
      g0, g1, g2, cg, pos1, pos2, target, out);
}

// Round 4
// 425.360 us; speedup vs baseline: 1.0219x; 1.0219x over previous
//
#include <hip/hip_runtime.h>
#include <cstdint>
#include <cstddef>

#define DEV static __device__ __forceinline__

typedef __attribute__((ext_vector_type(8))) short bf16x8_t;
typedef __attribute__((ext_vector_type(4))) float f32x4_t;

DEV unsigned short f2bf(float f) {
  union { float f; unsigned u; } v; v.f = f;
  unsigned r = v.u + 0x7fffu + ((v.u >> 16) & 1u);
  return (unsigned short)(r >> 16);
}

// async global->LDS, 16B per lane; LDS dest = wave-uniform base + lane*16
DEV void gl_lds16(const void* g, void* l) {
  __builtin_amdgcn_global_load_lds(
      (const __attribute__((address_space(1))) void*)g,
      (__attribute__((address_space(3))) void*)l,
      16, 0, 0);
}

// ---------------- prep: build_idx + casts + transposes, one launch --------
__global__ __launch_bounds__(256)
void prep_k(const int* __restrict__ target,
            int* __restrict__ idx1, int* __restrict__ pos1,
            int* __restrict__ idx2, int* __restrict__ pos2,
            int* __restrict__ cnts,
            const float* __restrict__ p0, const float* __restrict__ p1,
            const float* __restrict__ p2, unsigned short* __restrict__ pAll,
            const float* __restrict__ s0, unsigned short* __restrict__ d0, int n0,
            const float* __restrict__ s1, unsigned short* __restrict__ d1, int n1,
            const float* __restrict__ s2, unsigned short* __restrict__ d2, int n2,
            const float* __restrict__ s3, unsigned short* __restrict__ d3, int n3,
            const float* __restrict__ s4, unsigned short* __restrict__ d4, int n4) {
  const int bid = blockIdx.x;
  const int tid = threadIdx.x;
  if (bid == 0) {
    __shared__ int c1, c2;
    if (tid == 0) { c1 = 0; c2 = 0; }
    __syncthreads();
    for (int i = tid; i < 2048; i += 256) {
      int t = target[i];
      if (t >= 20000 && t < 50000) {
        int p = atomicAdd(&c1, 1); idx1[p] = i; pos1[i] = p;
      } else if (t >= 50000) {
        int p = atomicAdd(&c2, 1); idx2[p] = i; pos2[i] = p;
      }
    }
    __syncthreads();
    if (tid == 0) { cnts[0] = c1; cnts[1] = c2; }
    return;
  }
  if (bid <= 1344) {
    __shared__ float tile[32][33];
    int b = bid - 1;
    const float* src; unsigned short* dst; int C, bx, by;
    if (b < 1024)      { src = p0; dst = pAll;               C = 1024; bx = b % 32; by = b / 32; }
    else if (b < 1280) { int q = b - 1024; src = p1; dst = pAll + 1024 * 1024; C = 256; bx = q % 8; by = q / 8; }
    else               { int q = b - 1280; src = p2; dst = pAll + 1280 * 1024; C = 64;  bx = q % 2; by = q / 2; }
    const int R = 1024;
    int tx = tid & 31, ty = tid >> 5;
    int c0 = bx * 32, r0 = by * 32;
    for (int yy = ty; yy < 32; yy += 8)
      tile[yy][tx] = src[(size_t)(r0 + yy) * C + (c0 + tx)];
    __syncthreads();
    for (int yy = ty; yy < 32; yy += 8)
      dst[(size_t)(c0 + yy) * R + (r0 + tx)] = f2bf(tile[tx][yy]);
    return;
  }
  int j = (bid - 1345) * 256 + tid;
  const float* s; unsigned short* d;
  if (j < n0) { s = s0; d = d0; }
  else { j -= n0;
    if (j < n1) { s = s1; d = d1; }
    else { j -= n1;
      if (j < n2) { s = s2; d = d2; }
      else { j -= n2;
        if (j < n3) { s = s3; d = d3; }
        else { j -= n3; if (j >= n4) return; s = s4; d = d4; }
      }
    }
  }
  float4 f = ((const float4*)s)[j];
  ushort4 o;
  o.x = f2bf(f.x); o.y = f2bf(f.y); o.z = f2bf(f.z); o.w = f2bf(f.w);
  ((ushort4*)d)[j] = o;
}

// ---------------- proj GEMM: Pall[2048,1344] = Hb @ pAll^T ----------------
__global__ __launch_bounds__(256)
void proj_gemm_k(const unsigned short* __restrict__ A,
                 const unsigned short* __restrict__ W,
                 unsigned short* __restrict__ Cout) {
  __shared__ __align__(16) unsigned short As[128 * 32];
  __shared__ __align__(16) unsigned short Bs[128 * 32];
  const int K = 1024, V = 1344;
  const int tm = blockIdx.x, tn = blockIdx.y;
  const int m0 = tm * 128, n0 = tn * 128;
  const int tid = threadIdx.x, wid = tid >> 6, lane = tid & 63;
  const int quad = lane >> 4, l16 = lane & 15;
  const int wr = wid >> 1, wc = wid & 1;

  f32x4_t acc[4][4];
  const f32x4_t zero4 = {0.f, 0.f, 0.f, 0.f};
#pragma unroll
  for (int i = 0; i < 4; ++i)
#pragma unroll
    for (int j = 0; j < 4; ++j) acc[i][j] = zero4;

  const int srow = wid * 32 + (lane >> 2);
  const int skk  = (lane & 3) * 8;
  const unsigned short* Ap0 = A + (size_t)(m0 + srow) * K + skk;
  const unsigned short* Ap1 = A + (size_t)(m0 + srow + 16) * K + skk;
  int wrow0 = n0 + srow;      if (wrow0 > V - 1) wrow0 = V - 1;
  int wrow1 = n0 + srow + 16; if (wrow1 > V - 1) wrow1 = V - 1;
  const unsigned short* Wp0 = W + (size_t)wrow0 * K + skk;
  const unsigned short* Wp1 = W + (size_t)wrow1 * K + skk;
  unsigned short* Asw = As + wid * 1024;
  unsigned short* Bsw = Bs + wid * 1024;

  for (int k0 = 0; k0 < K; k0 += 32) {
    gl_lds16(Ap0, Asw);
    gl_lds16(Ap1, Asw + 512);
    gl_lds16(Wp0, Bsw);
    gl_lds16(Wp1, Bsw + 512);
    Ap0 += 32; Ap1 += 32; Wp0 += 32; Wp1 += 32;
    __syncthreads();
    bf16x8_t af[4], bfr[4];
#pragma unroll
    for (int i = 0; i < 4; ++i)
      af[i] = *(const bf16x8_t*)(As + (size_t)(wr * 64 + i * 16 + l16) * 32 + quad * 8);
#pragma unroll
    for (int j = 0; j < 4; ++j)
      bfr[j] = *(const bf16x8_t*)(Bs + (size_t)(wc * 64 + j * 16 + l16) * 32 + quad * 8);
#pragma unroll
    for (int i = 0; i < 4; ++i)
#pragma unroll
      for (int j = 0; j < 4; ++j)
        acc[i][j] = __builtin_amdgcn_mfma_f32_16x16x32_bf16(af[i], bfr[j], acc[i][j], 0, 0, 0);
    __syncthreads();
  }
#pragma unroll
  for (int i = 0; i < 4; ++i)
#pragma unroll
    for (int j = 0; j < 4; ++j) {
      const int n = n0 + wc * 64 + j * 16 + l16;
      if (n < V) {
#pragma unroll
        for (int r = 0; r < 4; ++r) {
          const int m = m0 + wr * 64 + i * 16 + quad * 4 + r;
          Cout[(size_t)m * V + n] = f2bf(acc[i][j][r]);
        }
      }
    }
}

// ---------------- head GEMM: 256x256, pipelined-register 4-window ---------
// vs R2: (a) static 632-grid + stripe-major XCD swizzle RESTORED (R3's
// persistent pop destroyed W-stripe L2 locality: FETCH 75->140 MB);
// (b) register reads issued ONE WINDOW before their consuming MFMA so the
// LDS pipe overlaps the MFMA pipe: W0 {Af-lo+Bh reads; STB(E,1); MFMA
// Af-lo x Bl}, W1 {MFMA Af-lo x Bh; Af-hi reads; STA(E,1)}, W2 {STB(D,0);
// MFMA Af-hi x Bl; vmcnt(2)}, W3 {STA(D,0); Bl(next) reads; MFMA
// Af-hi x Bh}. One barrier per window (4/K-tile, was 8). No sched_barrier,
// no explicit lgkm in the loop: reads are compiler-visible, hipcc emits
// counted lgkmcnt per use. vmcnt(2) at W2-end (memory clobber pins the W3
// reads below it) guarantees the next tile's lo-fragment regions (staged
// q2/q3 of kt-1 and q0/q1 of kt) have landed. Register set identical to R2
// (Af[2][4], Bl[2][2], Bh[2][2]) -> no VGPR growth.
// Full-rank LDS swizzle (conflicts==0) unchanged.

#define SBAR() __builtin_amdgcn_s_barrier()

#define STA(BUF, HALF, KT)                                                    \
  {                                                                           \
    const unsigned short* g_ = aB0 + (size_t)(HALF) * (128 * 1344) + (KT) * 64; \
    char* d_ = (char*)SA[BUF][HALF] + ldsw;                                   \
    gl_lds16(g_, d_);                                                         \
    gl_lds16(g_ + 64 * 1344, d_ + 8192);                                      \
  }

#define STB(BUF, HALF, KT)                                                    \
  {                                                                           \
    char* d_ = (char*)SB[BUF][HALF] + ldsw;                                   \
    gl_lds16(bP##HALF##0 + (KT) * 64, d_);                                    \
    gl_lds16(bP##HALF##1 + (KT) * 64, d_ + 8192);                             \
  }

#define MMQ(mb, nb, BB)                                                       \
  {                                                                           \
    _Pragma("unroll") for (int mi = 0; mi < 4; ++mi) {                        \
      _Pragma("unroll") for (int nj = 0; nj < 2; ++nj) {                      \
        acc[(mb) + mi][(nb) + nj] = __builtin_amdgcn_mfma_f32_16x16x32_bf16(  \
            Af[0][mi], BB[0][nj], acc[(mb) + mi][(nb) + nj], 0, 0, 0);        \
        acc[(mb) + mi][(nb) + nj] = __builtin_amdgcn_mfma_f32_16x16x32_bf16(  \
            Af[1][mi], BB[1][nj], acc[(mb) + mi][(nb) + nj], 0, 0, 0);        \
      }                                                                       \
    }                                                                         \
  }

#define PH(D_, E_, KTV)                                                       \
  {                                                                           \
    const int kt_ = (KTV);                                                    \
    const int t1_ = (kt_ + 1 > 15) ? 15 : (kt_ + 1);                          \
    const int t2_ = (kt_ + 2 > 15) ? 15 : (kt_ + 2);                          \
    /* W0: Af-lo (same-window) + Bh (for W1); stage B[E].h1(kt+1) */          \
    _Pragma("unroll") for (int mi = 0; mi < 4; ++mi) {                        \
      Af[0][mi] = *(const bf16x8_t*)(pa##D_##a + mi * 2048);                  \
      Af[1][mi] = *(const bf16x8_t*)(pa##D_##b + mi * 2048);                  \
    }                                                                         \
    _Pragma("unroll") for (int nj = 0; nj < 2; ++nj) {                        \
      Bh[0][nj] = *(const bf16x8_t*)(pb##D_##a + (2 + nj) * 2048);            \
      Bh[1][nj] = *(const bf16x8_t*)(pb##D_##b + (2 + nj) * 2048);            \
    }                                                                         \
    STB(E_, 1, t1_);                                                          \
    __builtin_amdgcn_s_setprio(1); MMQ(0, 0, Bl); __builtin_amdgcn_s_setprio(0); \
    SBAR();                                                                   \
    /* W1: MFMA lo x Bh; then Af-hi (for W2); stage A[E].h1(kt+1) */          \
    __builtin_amdgcn_s_setprio(1); MMQ(0, 2, Bh); __builtin_amdgcn_s_setprio(0); \
    _Pragma("unroll") for (int mi = 0; mi < 4; ++mi) {                        \
      Af[0][mi] = *(const bf16x8_t*)(pa##D_##a + (4 + mi) * 2048);            \
      Af[1][mi] = *(const bf16x8_t*)(pa##D_##b + (4 + mi) * 2048);            \
    }                                                                         \
    STA(E_, 1, t1_);                                                          \
    SBAR();                                                                   \
    /* W2: stage B[D].h0(kt+2); MFMA hi x Bl; counted vmcnt gate */           \
    STB(D_, 0, t2_);                                                          \
    __builtin_amdgcn_s_setprio(1); MMQ(4, 0, Bl); __builtin_amdgcn_s_setprio(0); \
    asm volatile("s_waitcnt vmcnt(2)" ::: "memory");                          \
    SBAR();                                                                   \
    /* W3: stage A[D].h0(kt+2); Bl(next) (for next W0); MFMA hi x Bh */       \
    STA(D_, 0, t2_);                                                          \
    _Pragma("unroll") for (int nj = 0; nj < 2; ++nj) {                        \
      Bl[0][nj] = *(const bf16x8_t*)(pb##E_##a + nj * 2048);                  \
      Bl[1][nj] = *(const bf16x8_t*)(pb##E_##b + nj * 2048);                  \
    }                                                                         \
    __builtin_amdgcn_s_setprio(1); MMQ(4, 2, Bh); __builtin_amdgcn_s_setprio(0); \
    SBAR();                                                                   \
  }

#define PROLOGUE6()                                                           \
  { STB(0, 0, 0); STA(0, 0, 0); STB(0, 1, 0); STA(0, 1, 0);                   \
    STB(1, 0, 1); STA(1, 0, 1); }

__global__ __launch_bounds__(512, 2)
void head256_k(const unsigned short* __restrict__ Pall,
               const unsigned short* __restrict__ w0b,
               const float* __restrict__ b0, const float* __restrict__ cb,
               float* __restrict__ part0, float* __restrict__ g0,
               float* __restrict__ cg, const int* __restrict__ target) {
  __shared__ __align__(16) unsigned short SA[2][2][8192];  // [dbuf][half][128*64]
  __shared__ __align__(16) unsigned short SB[2][2][8192];

  const int V = 20002;
  // XCD swizzle: 632 blocks % 8 == 0 -> bijection; stripe-major so each
  // XCD's L2 holds ~10 consecutive W-stripes.
  const int bid = blockIdx.x;
  const int orig = (bid & 7) * 79 + (bid >> 3);
  const int mt = orig & 7, stripe = orig >> 3;
  const int m0 = mt * 256, n0 = stripe * 256;

  const int tid = threadIdx.x;
  const int wid = tid >> 6, lane = tid & 63;
  const int quad = lane >> 4, l16 = lane & 15;
  const int wr = wid >> 2, wc = wid & 3;

  // staging source decode (full-rank swizzle inverse): thread fills phys
  // bytes {tid*16, 8192+tid*16}; phys row tid>>3, phys slot tid&7 ->
  // logical col16 = slot ^ (row&7).
  const int r0  = tid >> 3;                       // phys row 0..63
  const int ibh = ((tid & 7) ^ (r0 & 7)) << 3;    // logical element col

  const unsigned short* aB0 = Pall + (size_t)(m0 + r0) * 1344 + ibh;
  int br00 = n0 + r0;            if (br00 > V - 1) br00 = V - 1;
  int br01 = n0 + r0 + 64;       if (br01 > V - 1) br01 = V - 1;
  int br10 = n0 + 128 + r0;      if (br10 > V - 1) br10 = V - 1;
  int br11 = n0 + 128 + r0 + 64; if (br11 > V - 1) br11 = V - 1;
  const unsigned short* bP00 = w0b + (size_t)br00 * 1024 + ibh;
  const unsigned short* bP01 = w0b + (size_t)br01 * 1024 + ibh;
  const unsigned short* bP10 = w0b + (size_t)br10 * 1024 + ibh;
  const unsigned short* bP11 = w0b + (size_t)br11 * 1024 + ibh;

  const int ldsw = wid * 1024;  // wave-uniform gl_lds dest base

  // swizzled ds_read lane offsets: slot = (quad+4kk) ^ (l16&7)
  const int aoff0 = l16 * 128 + ((quad ^ (l16 & 3)) << 4) + (((l16 >> 2) & 1) << 6);
  const int aoff1 = aoff0 ^ 64;  // kk=1 flips col16 bit2
  const char* pa0a = (const char*)SA[0][wr] + aoff0;
  const char* pa0b = (const char*)SA[0][wr] + aoff1;
  const char* pa1a = (const char*)SA[1][wr] + aoff0;
  const char* pa1b = (const char*)SA[1][wr] + aoff1;
  const char* pb0a = (const char*)SB[0][wc >> 1] + (wc & 1) * 8192 + aoff0;
  const char* pb0b = (const char*)SB[0][wc >> 1] + (wc & 1) * 8192 + aoff1;
  const char* pb1a = (const char*)SB[1][wc >> 1] + (wc & 1) * 8192 + aoff0;
  const char* pb1b = (const char*)SB[1][wc >> 1] + (wc & 1) * 8192 + aoff1;

  f32x4_t acc[8][4];
  const f32x4_t zero4 = {0.f, 0.f, 0.f, 0.f};
#pragma unroll
  for (int i = 0; i < 8; ++i)
#pragma unroll
    for (int j = 0; j < 4; ++j) acc[i][j] = zero4;

  bf16x8_t Af[2][4];   // current A half-fragments (lo then hi within K-tile)
  bf16x8_t Bl[2][2];   // B lo-fragments (read one window ahead)
  bf16x8_t Bh[2][2];   // B hi-fragments (read one window ahead)

  // prologue: kt0 all 4 half-tiles + kt1 {B0,A0}; vmcnt(4) -> kt0 landed.
  PROLOGUE6();
  asm volatile("s_waitcnt vmcnt(4)" ::: "memory");
  SBAR();
  // pre-read Bl(kt0) (W0 consumes it; schedule reads Bl at prior W3)
#pragma unroll
  for (int nj = 0; nj < 2; ++nj) {
    Bl[0][nj] = *(const bf16x8_t*)(pb0a + nj * 2048);
    Bl[1][nj] = *(const bf16x8_t*)(pb0b + nj * 2048);
  }

#pragma unroll 1
  for (int ktp = 0; ktp < 8; ++ktp) {
    const int kt0 = 2 * ktp;
    PH(0, 1, kt0);
    PH(1, 0, kt0 + 1);
  }

  // drain all staging + dangling reads before LDS reuse
  asm volatile("s_waitcnt vmcnt(0) lgkmcnt(0)" ::: "memory");
  SBAR();

  int nj[4]; float bj[4];
#pragma unroll
  for (int j = 0; j < 4; ++j) {
    nj[j] = n0 + wc * 64 + j * 16 + l16;
    bj[j] = (nj[j] < 20000) ? b0[nj[j]] : ((nj[j] < V) ? cb[nj[j] - 20000] : 0.f);
  }
  float* redf = (float*)&SA[0][0][0];  // 8 x 128 floats
#pragma unroll
  for (int i = 0; i < 8; ++i) {
#pragma unroll
    for (int r = 0; r < 4; ++r) {
      const int rloc = i * 16 + quad * 4 + r;  // 0..127 within wave's half
      const int token = m0 + wr * 128 + rloc;
      float v[4], sum = 0.f;
#pragma unroll
      for (int j = 0; j < 4; ++j) {
        v[j] = acc[i][j][r] + bj[j];
        if (nj[j] < V) sum += __expf(v[j]);
      }
#pragma unroll
      for (int off = 1; off < 16; off <<= 1)
        sum += __shfl_xor(sum, off, 64);
      if (l16 == 0) redf[(wr * 4 + wc) * 128 + rloc] = sum;
      const int t = target[token];
      const int gi = (t < 19999) ? t : 19999;
#pragma unroll
      for (int j = 0; j < 4; ++j) {
        if (nj[j] == gi) g0[token] = v[j];
        if (nj[j] == 20000) cg[2 * token]     = v[j];
        if (nj[j] == 20001) cg[2 * token + 1] = v[j];
      }
    }
  }
  __syncthreads();
  if (tid < 256) {
    const int wrr = tid >> 7, rr = tid & 127;
    const float s = redf[(wrr * 4 + 0) * 128 + rr] + redf[(wrr * 4 + 1) * 128 + rr]
                  + redf[(wrr * 4 + 2) * 128 + rr] + redf[(wrr * 4 + 3) * 128 + rr];
    part0[(size_t)(m0 + tid) * 79 + stripe] = s;
  }
}

#undef PH
#undef MMQ
#undef STA
#undef STB
#undef PROLOGUE6
#undef SBAR

// ---------------- stripe-persistent tail GEMM -----------------------------
template <int KT>
__global__ __launch_bounds__(256, 1)
void tail_stripe_k(const unsigned short* __restrict__ A, int ldA,
                   const unsigned short* __restrict__ W,
                   const float* __restrict__ bias, int V, int ntiles,
                   const int* __restrict__ rowidx,
                   const int* __restrict__ cnt_ptr,
                   float* __restrict__ partials,
                   float* __restrict__ gathered,
                   const int* __restrict__ target, int glo) {
  constexpr int NC = KT / 32;
  __shared__ __align__(16) unsigned short Ws[NC][128 * 32];
  __shared__ __align__(16) unsigned short As[NC][128 * 32];
  __shared__ float red[2][128];

  const int tn = blockIdx.x, n0 = tn * 128;
  const int Meff = *cnt_ptr;
  const int tid = threadIdx.x, wid = tid >> 6, lane = tid & 63;
  const int quad = lane >> 4, l16 = lane & 15;
  const int wr = wid >> 1, wc = wid & 1;
  const int srow = wid * 32 + (lane >> 2);
  const int skk  = (lane & 3) * 8;

  int wrow0 = n0 + srow;      if (wrow0 > V - 1) wrow0 = V - 1;
  int wrow1 = n0 + srow + 16; if (wrow1 > V - 1) wrow1 = V - 1;
#pragma unroll
  for (int c = 0; c < NC; ++c) {
    gl_lds16(W + (size_t)wrow0 * KT + c * 32 + skk, Ws[c] + wid * 1024);
    gl_lds16(W + (size_t)wrow1 * KT + c * 32 + skk, Ws[c] + wid * 1024 + 512);
  }

  int nj[4]; float bj[4];
#pragma unroll
  for (int j = 0; j < 4; ++j) {
    nj[j] = n0 + wc * 64 + j * 16 + l16;
    bj[j] = (nj[j] < V) ? bias[nj[j]] : 0.f;
  }

  const int nm = (Meff + 127) >> 7;
  for (int m = 0; m < nm; ++m) {
    const int m0 = m * 128;
    int ar0 = m0 + srow;      if (ar0 > Meff - 1) ar0 = Meff - 1;
    int ar1 = m0 + srow + 16; if (ar1 > Meff - 1) ar1 = Meff - 1;
    ar0 = rowidx[ar0]; ar1 = rowidx[ar1];
#pragma unroll
    for (int c = 0; c < NC; ++c) {
      gl_lds16(A + (size_t)ar0 * ldA + c * 32 + skk, As[c] + wid * 1024);
      gl_lds16(A + (size_t)ar1 * ldA + c * 32 + skk, As[c] + wid * 1024 + 512);
    }
    __syncthreads();

    f32x4_t acc[4][4];
    const f32x4_t zero4 = {0.f, 0.f, 0.f, 0.f};
#pragma unroll
    for (int i = 0; i < 4; ++i)
#pragma unroll
      for (int j = 0; j < 4; ++j) acc[i][j] = zero4;
#pragma unroll
    for (int c = 0; c < NC; ++c) {
      bf16x8_t af[4], bfr[4];
#pragma unroll
      for (int i = 0; i < 4; ++i)
        af[i] = *(const bf16x8_t*)(As[c] + (size_t)(wr * 64 + i * 16 + l16) * 32 + quad * 8);
#pragma unroll
      for (int j = 0; j < 4; ++j)
        bfr[j] = *(const bf16x8_t*)(Ws[c] + (size_t)(wc * 64 + j * 16 + l16) * 32 + quad * 8);
#pragma unroll
      for (int i = 0; i < 4; ++i)
#pragma unroll
        for (int j = 0; j < 4; ++j)
          acc[i][j] = __builtin_amdgcn_mfma_f32_16x16x32_bf16(af[i], bfr[j], acc[i][j], 0, 0, 0);
    }

#pragma unroll
    for (int i = 0; i < 4; ++i) {
#pragma unroll
      for (int r = 0; r < 4; ++r) {
        const int row = wr * 64 + i * 16 + quad * 4 + r;
        const int gr = m0 + row;
        const int grc = (gr < Meff) ? gr : (Meff - 1);
        const int token = rowidx[grc];
        float v[4], sum = 0.f;
#pragma unroll
        for (int j = 0; j < 4; ++j) {
          v[j] = acc[i][j][r] + bj[j];
          if (nj[j] < V) sum += __expf(v[j]);
        }
#pragma unroll
        for (int off = 1; off < 16; off <<= 1)
          sum += __shfl_xor(sum, off, 64);
        if (l16 == 0) red[wc][row] = sum;
        const int gi = target[token] - glo;
#pragma unroll
        for (int j = 0; j < 4; ++j)
          if (nj[j] == gi) gathered[token] = v[j];
      }
    }
    __syncthreads();
    if (tid < 128 && (m0 + tid) < Meff)
      partials[(size_t)(m0 + tid) * ntiles + tn] = red[0][tid] + red[1][tid];
  }
}

// ---------------- combine: wave per token ----------------
__global__ __launch_bounds__(256)
void combine_k(const float* __restrict__ part0,
               const float* __restrict__ part1, int nt1,
               const float* __restrict__ part2, int nt2,
               const float* __restrict__ g0, const float* __restrict__ g1,
               const float* __restrict__ g2, const float* __restrict__ cg,
               const int* __restrict__ pos1, const int* __restrict__ pos2,
               const int* __restrict__ target, float* __restrict__ out) {
  const int w = threadIdx.x >> 6, lane = threadIdx.x & 63;
  const int token = blockIdx.x * 4 + w;
  const int t = target[token];

  float S = 0.f;
  for (int i = lane; i < 79; i += 64)
    S += part0[(size_t)token * 79 + i];
#pragma unroll
  for (int off = 1; off < 64; off <<= 1)
    S += __shfl_xor(S, off, 64);
  const float lse_head = __logf(S);

  float res;
  if (t < 20000) {
    res = lse_head - g0[token];
  } else {
    const float* pt; int nt; float gv, ch; int row;
    if (t < 50000) { pt = part1; nt = nt1; gv = g1[token]; ch = cg[2 * token + 1]; row = pos1[token]; }
    else           { pt = part2; nt = nt2; gv = g2[token]; ch = cg[2 * token];     row = pos2[token]; }
    float S2 = 0.f;
    for (int i = lane; i < nt; i += 64)
      S2 += pt[(size_t)row * nt + i];
#pragma unroll
    for (int off = 1; off < 64; off <<= 1)
      S2 += __shfl_xor(S2, off, 64);
    float lse_t = __logf(S2);
    res = -((ch - lse_head) + (gv - lse_t));
  }
  if (lane == 0) out[token] = res;
}

extern "C" void kernel_launch(void* const* d_in, const int* in_sizes, int n_in,
                              void* d_out, int out_size, void* d_ws, size_t ws_size,
                              hipStream_t stream) {
  (void)in_sizes; (void)n_in; (void)out_size; (void)ws_size;
  const float* hidden = (const float*)d_in[0];
  const int*   target = (const int*)d_in[1];
  const float* w0     = (const float*)d_in[2];
  const float* b0     = (const float*)d_in[3];
  const float* cw     = (const float*)d_in[4];
  const float* cb     = (const float*)d_in[5];
  const float* proj0  = (const float*)d_in[6];
  const float* w1     = (const float*)d_in[7];
  const float* b1     = (const float*)d_in[8];
  const float* proj1  = (const float*)d_in[9];
  const float* w2     = (const float*)d_in[10];
  const float* b2     = (const float*)d_in[11];
  const float* proj2  = (const float*)d_in[12];
  float* out = (float*)d_out;

  const int NT1 = 235, NT2 = 391;

  char* p = (char*)d_ws;
  auto alloc = [&](size_t bytes) {
    char* r = p; p += (bytes + 255) & ~(size_t)255; return r;
  };
  unsigned short* Hb   = (unsigned short*)alloc(2048ull * 1024 * 2);
  unsigned short* pAll = (unsigned short*)alloc(1344ull * 1024 * 2);
  unsigned short* w0b  = (unsigned short*)alloc(20002ull * 1024 * 2);
  unsigned short* w1b  = (unsigned short*)alloc(30000ull * 256 * 2);
  unsigned short* w2b  = (unsigned short*)alloc(50000ull * 64 * 2);
  unsigned short* Pall = (unsigned short*)alloc(2048ull * 1344 * 2);
  float* part0 = (float*)alloc(2048ull * 79 * 4);
  float* part1 = (float*)alloc(2048ull * NT1 * 4);
  float* part2 = (float*)alloc(2048ull * NT2 * 4);
  float* g0 = (float*)alloc(2048 * 4);
  float* g1 = (float*)alloc(2048 * 4);
  float* g2 = (float*)alloc(2048 * 4);
  float* cg = (float*)alloc(2048 * 2 * 4);
  int* idx1 = (int*)alloc(2048 * 4);
  int* pos1 = (int*)alloc(2048 * 4);
  int* idx2 = (int*)alloc(2048 * 4);
  int* pos2 = (int*)alloc(2048 * 4);
  int* cnts = (int*)alloc(2 * 4);

  const int c_h = 2048 * 1024 / 4, c_w0 = 20000 * 1024 / 4, c_cw = 2048 / 4,
            c_w1 = 30000 * 256 / 4, c_w2 = 50000 * 64 / 4;
  const int ctot = c_h + c_w0 + c_cw + c_w1 + c_w2;
  const int nb_cast = (ctot + 255) / 256;
  prep_k<<<1 + 1344 + nb_cast, 256, 0, stream>>>(
      target, idx1, pos1, idx2, pos2, cnts,
      proj0, proj1, proj2, pAll,
      hidden, Hb, c_h,
      w0, w0b, c_w0,
      cw, w0b + 20000ull * 1024, c_cw,
      w1, w1b, c_w1,
      w2, w2b, c_w2);

  // merged projections: Pall[2048,1344] = Hb @ pAll^T
  proj_gemm_k<<<dim3(16, 11), 256, 0, stream>>>(Hb, pAll, Pall);

  // head: 256^2 pipelined GEMM, grid = 8 m-tiles x 79 stripes (XCD swizzle)
  head256_k<<<632, 512, 0, stream>>>(Pall, w0b, b0, cb, part0, g0, cg, target);

  // tails: one block per stripe, W persistent in LDS, m-loop inside
  tail_stripe_k<256><<<NT1, 256, 0, stream>>>(
      Pall + 1024, 1344, w1b, b1, 30000, NT1, idx1, cnts + 0,
      part1, g1, target, 20000);
  tail_stripe_k<64><<<NT2, 256, 0, stream>>>(
      Pall + 1280, 1344, w2b, b2, 50000, NT2, idx2, cnts + 1,
      part2, g2, target, 50000);

  combine_k<<<512, 256, 0, stream>>>(part0, part1, NT1, part2, NT2,
      g0, g1, g2, cg, pos1, pos2, target, out);
}

// Round 5
// 418.348 us; speedup vs baseline: 1.0390x; 1.0168x over previous
//
#include <hip/hip_runtime.h>
#include <cstdint>
#include <cstddef>

#define DEV static __device__ __forceinline__

typedef __attribute__((ext_vector_type(8))) short bf16x8_t;
typedef __attribute__((ext_vector_type(4))) float f32x4_t;

DEV unsigned short f2bf(float f) {
  union { float f; unsigned u; } v; v.f = f;
  unsigned r = v.u + 0x7fffu + ((v.u >> 16) & 1u);
  return (unsigned short)(r >> 16);
}

// async global->LDS, 16B per lane; LDS dest = wave-uniform base + lane*16
DEV void gl_lds16(const void* g, void* l) {
  __builtin_amdgcn_global_load_lds(
      (const __attribute__((address_space(1))) void*)g,
      (__attribute__((address_space(3))) void*)l,
      16, 0, 0);
}

// ---------------- prep: build_idx + casts + transposes, one launch --------
__global__ __launch_bounds__(256)
void prep_k(const int* __restrict__ target,
            int* __restrict__ idx1, int* __restrict__ pos1,
            int* __restrict__ idx2, int* __restrict__ pos2,
            int* __restrict__ cnts,
            const float* __restrict__ p0, const float* __restrict__ p1,
            const float* __restrict__ p2, unsigned short* __restrict__ pAll,
            const float* __restrict__ s0, unsigned short* __restrict__ d0, int n0,
            const float* __restrict__ s1, unsigned short* __restrict__ d1, int n1,
            const float* __restrict__ s2, unsigned short* __restrict__ d2, int n2,
            const float* __restrict__ s3, unsigned short* __restrict__ d3, int n3,
            const float* __restrict__ s4, unsigned short* __restrict__ d4, int n4) {
  const int bid = blockIdx.x;
  const int tid = threadIdx.x;
  if (bid == 0) {
    __shared__ int c1, c2;
    if (tid == 0) { c1 = 0; c2 = 0; }
    __syncthreads();
    for (int i = tid; i < 2048; i += 256) {
      int t = target[i];
      if (t >= 20000 && t < 50000) {
        int p = atomicAdd(&c1, 1); idx1[p] = i; pos1[i] = p;
      } else if (t >= 50000) {
        int p = atomicAdd(&c2, 1); idx2[p] = i; pos2[i] = p;
      }
    }
    __syncthreads();
    if (tid == 0) { cnts[0] = c1; cnts[1] = c2; }
    return;
  }
  if (bid <= 1344) {
    __shared__ float tile[32][33];
    int b = bid - 1;
    const float* src; unsigned short* dst; int C, bx, by;
    if (b < 1024)      { src = p0; dst = pAll;               C = 1024; bx = b % 32; by = b / 32; }
    else if (b < 1280) { int q = b - 1024; src = p1; dst = pAll + 1024 * 1024; C = 256; bx = q % 8; by = q / 8; }
    else               { int q = b - 1280; src = p2; dst = pAll + 1280 * 1024; C = 64;  bx = q % 2; by = q / 2; }
    const int R = 1024;
    int tx = tid & 31, ty = tid >> 5;
    int c0 = bx * 32, r0 = by * 32;
    for (int yy = ty; yy < 32; yy += 8)
      tile[yy][tx] = src[(size_t)(r0 + yy) * C + (c0 + tx)];
    __syncthreads();
    for (int yy = ty; yy < 32; yy += 8)
      dst[(size_t)(c0 + yy) * R + (r0 + tx)] = f2bf(tile[tx][yy]);
    return;
  }
  int j = (bid - 1345) * 256 + tid;
  const float* s; unsigned short* d;
  if (j < n0) { s = s0; d = d0; }
  else { j -= n0;
    if (j < n1) { s = s1; d = d1; }
    else { j -= n1;
      if (j < n2) { s = s2; d = d2; }
      else { j -= n2;
        if (j < n3) { s = s3; d = d3; }
        else { j -= n3; if (j >= n4) return; s = s4; d = d4; }
      }
    }
  }
  float4 f = ((const float4*)s)[j];
  ushort4 o;
  o.x = f2bf(f.x); o.y = f2bf(f.y); o.z = f2bf(f.z); o.w = f2bf(f.w);
  ((ushort4*)d)[j] = o;
}

// ---------------- proj GEMM: Pall[2048,1344] = Hb @ pAll^T ----------------
__global__ __launch_bounds__(256)
void proj_gemm_k(const unsigned short* __restrict__ A,
                 const unsigned short* __restrict__ W,
                 unsigned short* __restrict__ Cout) {
  __shared__ __align__(16) unsigned short As[128 * 32];
  __shared__ __align__(16) unsigned short Bs[128 * 32];
  const int K = 1024, V = 1344;
  const int tm = blockIdx.x, tn = blockIdx.y;
  const int m0 = tm * 128, n0 = tn * 128;
  const int tid = threadIdx.x, wid = tid >> 6, lane = tid & 63;
  const int quad = lane >> 4, l16 = lane & 15;
  const int wr = wid >> 1, wc = wid & 1;

  f32x4_t acc[4][4];
  const f32x4_t zero4 = {0.f, 0.f, 0.f, 0.f};
#pragma unroll
  for (int i = 0; i < 4; ++i)
#pragma unroll
    for (int j = 0; j < 4; ++j) acc[i][j] = zero4;

  const int srow = wid * 32 + (lane >> 2);
  const int skk  = (lane & 3) * 8;
  const unsigned short* Ap0 = A + (size_t)(m0 + srow) * K + skk;
  const unsigned short* Ap1 = A + (size_t)(m0 + srow + 16) * K + skk;
  int wrow0 = n0 + srow;      if (wrow0 > V - 1) wrow0 = V - 1;
  int wrow1 = n0 + srow + 16; if (wrow1 > V - 1) wrow1 = V - 1;
  const unsigned short* Wp0 = W + (size_t)wrow0 * K + skk;
  const unsigned short* Wp1 = W + (size_t)wrow1 * K + skk;
  unsigned short* Asw = As + wid * 1024;
  unsigned short* Bsw = Bs + wid * 1024;

  for (int k0 = 0; k0 < K; k0 += 32) {
    gl_lds16(Ap0, Asw);
    gl_lds16(Ap1, Asw + 512);
    gl_lds16(Wp0, Bsw);
    gl_lds16(Wp1, Bsw + 512);
    Ap0 += 32; Ap1 += 32; Wp0 += 32; Wp1 += 32;
    __syncthreads();
    bf16x8_t af[4], bfr[4];
#pragma unroll
    for (int i = 0; i < 4; ++i)
      af[i] = *(const bf16x8_t*)(As + (size_t)(wr * 64 + i * 16 + l16) * 32 + quad * 8);
#pragma unroll
    for (int j = 0; j < 4; ++j)
      bfr[j] = *(const bf16x8_t*)(Bs + (size_t)(wc * 64 + j * 16 + l16) * 32 + quad * 8);
#pragma unroll
    for (int i = 0; i < 4; ++i)
#pragma unroll
      for (int j = 0; j < 4; ++j)
        acc[i][j] = __builtin_amdgcn_mfma_f32_16x16x32_bf16(af[i], bfr[j], acc[i][j], 0, 0, 0);
    __syncthreads();
  }
#pragma unroll
  for (int i = 0; i < 4; ++i)
#pragma unroll
    for (int j = 0; j < 4; ++j) {
      const int n = n0 + wc * 64 + j * 16 + l16;
      if (n < V) {
#pragma unroll
        for (int r = 0; r < 4; ++r) {
          const int m = m0 + wr * 64 + i * 16 + quad * 4 + r;
          Cout[(size_t)m * V + n] = f2bf(acc[i][j][r]);
        }
      }
    }
}

// ================= fused head + tails (one launch, 512 thr) ===============
// bids [0,632): head 256x256 pipelined GEMM (byte-identical R4 schedule).
// bids [632,867): tail1 stripes (KT=256).  [867,1258): tail2 (KT=64).
// Tail bodies keep their 256-thread structure; waves 4-7 idle through
// barriers (those CUs were idle during head's last round anyway).
// Shared memory: one 132096-byte union (head 128K + redf alias; tail1 129K).

#define SBAR() __builtin_amdgcn_s_barrier()

#define STA(BUF, HALF, KT)                                                    \
  {                                                                           \
    const unsigned short* g_ = aB0 + (size_t)(HALF) * (128 * 1344) + (KT) * 64; \
    char* d_ = (char*)SA[BUF][HALF] + ldsw;                                   \
    gl_lds16(g_, d_);                                                         \
    gl_lds16(g_ + 64 * 1344, d_ + 8192);                                      \
  }

#define STB(BUF, HALF, KT)                                                    \
  {                                                                           \
    char* d_ = (char*)SB[BUF][HALF] + ldsw;                                   \
    gl_lds16(bP##HALF##0 + (KT) * 64, d_);                                    \
    gl_lds16(bP##HALF##1 + (KT) * 64, d_ + 8192);                             \
  }

#define MMQ(mb, nb, BB)                                                       \
  {                                                                           \
    _Pragma("unroll") for (int mi = 0; mi < 4; ++mi) {                        \
      _Pragma("unroll") for (int nj = 0; nj < 2; ++nj) {                      \
        acc[(mb) + mi][(nb) + nj] = __builtin_amdgcn_mfma_f32_16x16x32_bf16(  \
            Af[0][mi], BB[0][nj], acc[(mb) + mi][(nb) + nj], 0, 0, 0);        \
        acc[(mb) + mi][(nb) + nj] = __builtin_amdgcn_mfma_f32_16x16x32_bf16(  \
            Af[1][mi], BB[1][nj], acc[(mb) + mi][(nb) + nj], 0, 0, 0);        \
      }                                                                       \
    }                                                                         \
  }

#define PH(D_, E_, KTV)                                                       \
  {                                                                           \
    const int kt_ = (KTV);                                                    \
    const int t1_ = (kt_ + 1 > 15) ? 15 : (kt_ + 1);                          \
    const int t2_ = (kt_ + 2 > 15) ? 15 : (kt_ + 2);                          \
    /* W0: Af-lo (same-window) + Bh (for W1); stage B[E].h1(kt+1) */          \
    _Pragma("unroll") for (int mi = 0; mi < 4; ++mi) {                        \
      Af[0][mi] = *(const bf16x8_t*)(pa##D_##a + mi * 2048);                  \
      Af[1][mi] = *(const bf16x8_t*)(pa##D_##b + mi * 2048);                  \
    }                                                                         \
    _Pragma("unroll") for (int nj = 0; nj < 2; ++nj) {                        \
      Bh[0][nj] = *(const bf16x8_t*)(pb##D_##a + (2 + nj) * 2048);            \
      Bh[1][nj] = *(const bf16x8_t*)(pb##D_##b + (2 + nj) * 2048);            \
    }                                                                         \
    STB(E_, 1, t1_);                                                          \
    __builtin_amdgcn_s_setprio(1); MMQ(0, 0, Bl); __builtin_amdgcn_s_setprio(0); \
    SBAR();                                                                   \
    /* W1: MFMA lo x Bh; then Af-hi (for W2); stage A[E].h1(kt+1) */          \
    __builtin_amdgcn_s_setprio(1); MMQ(0, 2, Bh); __builtin_amdgcn_s_setprio(0); \
    _Pragma("unroll") for (int mi = 0; mi < 4; ++mi) {                        \
      Af[0][mi] = *(const bf16x8_t*)(pa##D_##a + (4 + mi) * 2048);            \
      Af[1][mi] = *(const bf16x8_t*)(pa##D_##b + (4 + mi) * 2048);            \
    }                                                                         \
    STA(E_, 1, t1_);                                                          \
    SBAR();                                                                   \
    /* W2: stage B[D].h0(kt+2); MFMA hi x Bl; counted vmcnt gate */           \
    STB(D_, 0, t2_);                                                          \
    __builtin_amdgcn_s_setprio(1); MMQ(4, 0, Bl); __builtin_amdgcn_s_setprio(0); \
    asm volatile("s_waitcnt vmcnt(2)" ::: "memory");                          \
    SBAR();                                                                   \
    /* W3: stage A[D].h0(kt+2); Bl(next) (for next W0); MFMA hi x Bh */       \
    STA(D_, 0, t2_);                                                          \
    _Pragma("unroll") for (int nj = 0; nj < 2; ++nj) {                        \
      Bl[0][nj] = *(const bf16x8_t*)(pb##E_##a + nj * 2048);                  \
      Bl[1][nj] = *(const bf16x8_t*)(pb##E_##b + nj * 2048);                  \
    }                                                                         \
    __builtin_amdgcn_s_setprio(1); MMQ(4, 2, Bh); __builtin_amdgcn_s_setprio(0); \
    SBAR();                                                                   \
  }

#define PROLOGUE6()                                                           \
  { STB(0, 0, 0); STA(0, 0, 0); STB(0, 1, 0); STA(0, 1, 0);                   \
    STB(1, 0, 1); STA(1, 0, 1); }

typedef unsigned short lds_half_t[2][8192];

DEV void head_body(char* UB, int bid,
                   const unsigned short* __restrict__ Pall,
                   const unsigned short* __restrict__ w0b,
                   const float* __restrict__ b0, const float* __restrict__ cb,
                   float* __restrict__ part0, float* __restrict__ g0,
                   float* __restrict__ cg, const int* __restrict__ target) {
  lds_half_t* SA = (lds_half_t*)UB;              // [2][2][8192] shorts, 64 KB
  lds_half_t* SB = (lds_half_t*)(UB + 65536);    // 64 KB

  const int V = 20002;
  // XCD swizzle: 632 blocks % 8 == 0 -> bijection; stripe-major so each
  // XCD's L2 holds ~10 consecutive W-stripes.
  const int orig = (bid & 7) * 79 + (bid >> 3);
  const int mt = orig & 7, stripe = orig >> 3;
  const int m0 = mt * 256, n0 = stripe * 256;

  const int tid = threadIdx.x;
  const int wid = tid >> 6, lane = tid & 63;
  const int quad = lane >> 4, l16 = lane & 15;
  const int wr = wid >> 2, wc = wid & 3;

  // staging source decode (full-rank swizzle inverse): thread fills phys
  // bytes {tid*16, 8192+tid*16}; phys row tid>>3, phys slot tid&7 ->
  // logical col16 = slot ^ (row&7).
  const int r0  = tid >> 3;                       // phys row 0..63
  const int ibh = ((tid & 7) ^ (r0 & 7)) << 3;    // logical element col

  const unsigned short* aB0 = Pall + (size_t)(m0 + r0) * 1344 + ibh;
  int br00 = n0 + r0;            if (br00 > V - 1) br00 = V - 1;
  int br01 = n0 + r0 + 64;       if (br01 > V - 1) br01 = V - 1;
  int br10 = n0 + 128 + r0;      if (br10 > V - 1) br10 = V - 1;
  int br11 = n0 + 128 + r0 + 64; if (br11 > V - 1) br11 = V - 1;
  const unsigned short* bP00 = w0b + (size_t)br00 * 1024 + ibh;
  const unsigned short* bP01 = w0b + (size_t)br01 * 1024 + ibh;
  const unsigned short* bP10 = w0b + (size_t)br10 * 1024 + ibh;
  const unsigned short* bP11 = w0b + (size_t)br11 * 1024 + ibh;

  const int ldsw = wid * 1024;  // wave-uniform gl_lds dest base

  // swizzled ds_read lane offsets: slot = (quad+4kk) ^ (l16&7)
  const int aoff0 = l16 * 128 + ((quad ^ (l16 & 3)) << 4) + (((l16 >> 2) & 1) << 6);
  const int aoff1 = aoff0 ^ 64;  // kk=1 flips col16 bit2
  const char* pa0a = (const char*)SA[0][wr] + aoff0;
  const char* pa0b = (const char*)SA[0][wr] + aoff1;
  const char* pa1a = (const char*)SA[1][wr] + aoff0;
  const char* pa1b = (const char*)SA[1][wr] + aoff1;
  const char* pb0a = (const char*)SB[0][wc >> 1] + (wc & 1) * 8192 + aoff0;
  const char* pb0b = (const char*)SB[0][wc >> 1] + (wc & 1) * 8192 + aoff1;
  const char* pb1a = (const char*)SB[1][wc >> 1] + (wc & 1) * 8192 + aoff0;
  const char* pb1b = (const char*)SB[1][wc >> 1] + (wc & 1) * 8192 + aoff1;

  f32x4_t acc[8][4];
  const f32x4_t zero4 = {0.f, 0.f, 0.f, 0.f};
#pragma unroll
  for (int i = 0; i < 8; ++i)
#pragma unroll
    for (int j = 0; j < 4; ++j) acc[i][j] = zero4;

  bf16x8_t Af[2][4];   // current A half-fragments (lo then hi within K-tile)
  bf16x8_t Bl[2][2];   // B lo-fragments (read one window ahead)
  bf16x8_t Bh[2][2];   // B hi-fragments (read one window ahead)

  // prologue: kt0 all 4 half-tiles + kt1 {B0,A0}; vmcnt(4) -> kt0 landed.
  PROLOGUE6();
  asm volatile("s_waitcnt vmcnt(4)" ::: "memory");
  SBAR();
  // pre-read Bl(kt0) (W0 consumes it; schedule reads Bl at prior W3)
#pragma unroll
  for (int nj = 0; nj < 2; ++nj) {
    Bl[0][nj] = *(const bf16x8_t*)(pb0a + nj * 2048);
    Bl[1][nj] = *(const bf16x8_t*)(pb0b + nj * 2048);
  }

#pragma unroll 1
  for (int ktp = 0; ktp < 8; ++ktp) {
    const int kt0 = 2 * ktp;
    PH(0, 1, kt0);
    PH(1, 0, kt0 + 1);
  }

  // drain all staging + dangling reads before LDS reuse
  asm volatile("s_waitcnt vmcnt(0) lgkmcnt(0)" ::: "memory");
  SBAR();

  int nj[4]; float bj[4];
#pragma unroll
  for (int j = 0; j < 4; ++j) {
    nj[j] = n0 + wc * 64 + j * 16 + l16;
    bj[j] = (nj[j] < 20000) ? b0[nj[j]] : ((nj[j] < V) ? cb[nj[j] - 20000] : 0.f);
  }
  float* redf = (float*)UB;  // 8 x 128 floats (aliases SA; drained above)
#pragma unroll
  for (int i = 0; i < 8; ++i) {
#pragma unroll
    for (int r = 0; r < 4; ++r) {
      const int rloc = i * 16 + quad * 4 + r;  // 0..127 within wave's half
      const int token = m0 + wr * 128 + rloc;
      float v[4], sum = 0.f;
#pragma unroll
      for (int j = 0; j < 4; ++j) {
        v[j] = acc[i][j][r] + bj[j];
        if (nj[j] < V) sum += __expf(v[j]);
      }
#pragma unroll
      for (int off = 1; off < 16; off <<= 1)
        sum += __shfl_xor(sum, off, 64);
      if (l16 == 0) redf[(wr * 4 + wc) * 128 + rloc] = sum;
      const int t = target[token];
      const int gi = (t < 19999) ? t : 19999;
#pragma unroll
      for (int j = 0; j < 4; ++j) {
        if (nj[j] == gi) g0[token] = v[j];
        if (nj[j] == 20000) cg[2 * token]     = v[j];
        if (nj[j] == 20001) cg[2 * token + 1] = v[j];
      }
    }
  }
  __syncthreads();
  if (tid < 256) {
    const int wrr = tid >> 7, rr = tid & 127;
    const float s = redf[(wrr * 4 + 0) * 128 + rr] + redf[(wrr * 4 + 1) * 128 + rr]
                  + redf[(wrr * 4 + 2) * 128 + rr] + redf[(wrr * 4 + 3) * 128 + rr];
    part0[(size_t)(m0 + tid) * 79 + stripe] = s;
  }
}

#undef PH
#undef MMQ
#undef STA
#undef STB
#undef PROLOGUE6
#undef SBAR

// ---------------- tail body (256-thread logic inside 512-thread block) ----
template <int KT>
DEV void tail_body(char* UB, int tn,
                   const unsigned short* __restrict__ A, int ldA,
                   const unsigned short* __restrict__ W,
                   const float* __restrict__ bias, int V, int ntiles,
                   const int* __restrict__ rowidx,
                   const int* __restrict__ cnt_ptr,
                   float* __restrict__ partials,
                   float* __restrict__ gathered,
                   const int* __restrict__ target, int glo) {
  constexpr int NC = KT / 32;
  unsigned short (*Ws)[128 * 32] = (unsigned short (*)[128 * 32])UB;
  unsigned short (*As)[128 * 32] = (unsigned short (*)[128 * 32])(UB + NC * 8192);
  float (*red)[128] = (float (*)[128])(UB + 2 * NC * 8192);

  const int n0 = tn * 128;
  const int Meff = *cnt_ptr;
  const int tid = threadIdx.x;
  const bool act = tid < 256;
  const int wid = tid >> 6, lane = tid & 63;
  const int quad = lane >> 4, l16 = lane & 15;
  const int wr = wid >> 1, wc = wid & 1;
  const int srow = wid * 32 + (lane >> 2);
  const int skk  = (lane & 3) * 8;

  int wrow0 = n0 + srow;      if (wrow0 > V - 1) wrow0 = V - 1;
  int wrow1 = n0 + srow + 16; if (wrow1 > V - 1) wrow1 = V - 1;
  if (act) {
#pragma unroll
    for (int c = 0; c < NC; ++c) {
      gl_lds16(W + (size_t)wrow0 * KT + c * 32 + skk, Ws[c] + wid * 1024);
      gl_lds16(W + (size_t)wrow1 * KT + c * 32 + skk, Ws[c] + wid * 1024 + 512);
    }
  }

  int nj[4]; float bj[4];
#pragma unroll
  for (int j = 0; j < 4; ++j) {
    nj[j] = n0 + wc * 64 + j * 16 + l16;
    bj[j] = (act && nj[j] < V) ? bias[nj[j]] : 0.f;
  }

  const int nm = (Meff + 127) >> 7;
  for (int m = 0; m < nm; ++m) {
    const int m0 = m * 128;
    if (act) {
      int ar0 = m0 + srow;      if (ar0 > Meff - 1) ar0 = Meff - 1;
      int ar1 = m0 + srow + 16; if (ar1 > Meff - 1) ar1 = Meff - 1;
      ar0 = rowidx[ar0]; ar1 = rowidx[ar1];
#pragma unroll
      for (int c = 0; c < NC; ++c) {
        gl_lds16(A + (size_t)ar0 * ldA + c * 32 + skk, As[c] + wid * 1024);
        gl_lds16(A + (size_t)ar1 * ldA + c * 32 + skk, As[c] + wid * 1024 + 512);
      }
    }
    __syncthreads();

    if (act) {
      f32x4_t acc[4][4];
      const f32x4_t zero4 = {0.f, 0.f, 0.f, 0.f};
#pragma unroll
      for (int i = 0; i < 4; ++i)
#pragma unroll
        for (int j = 0; j < 4; ++j) acc[i][j] = zero4;
#pragma unroll
      for (int c = 0; c < NC; ++c) {
        bf16x8_t af[4], bfr[4];
#pragma unroll
        for (int i = 0; i < 4; ++i)
          af[i] = *(const bf16x8_t*)(As[c] + (size_t)(wr * 64 + i * 16 + l16) * 32 + quad * 8);
#pragma unroll
        for (int j = 0; j < 4; ++j)
          bfr[j] = *(const bf16x8_t*)(Ws[c] + (size_t)(wc * 64 + j * 16 + l16) * 32 + quad * 8);
#pragma unroll
        for (int i = 0; i < 4; ++i)
#pragma unroll
          for (int j = 0; j < 4; ++j)
            acc[i][j] = __builtin_amdgcn_mfma_f32_16x16x32_bf16(af[i], bfr[j], acc[i][j], 0, 0, 0);
      }

#pragma unroll
      for (int i = 0; i < 4; ++i) {
#pragma unroll
        for (int r = 0; r < 4; ++r) {
          const int row = wr * 64 + i * 16 + quad * 4 + r;
          const int gr = m0 + row;
          const int grc = (gr < Meff) ? gr : (Meff - 1);
          const int token = rowidx[grc];
          float v[4], sum = 0.f;
#pragma unroll
          for (int j = 0; j < 4; ++j) {
            v[j] = acc[i][j][r] + bj[j];
            if (nj[j] < V) sum += __expf(v[j]);
          }
#pragma unroll
          for (int off = 1; off < 16; off <<= 1)
            sum += __shfl_xor(sum, off, 64);
          if (l16 == 0) red[wc][row] = sum;
          const int gi = target[token] - glo;
#pragma unroll
          for (int j = 0; j < 4; ++j)
            if (nj[j] == gi) gathered[token] = v[j];
        }
      }
    }
    __syncthreads();
    if (tid < 128 && (m0 + tid) < Meff)
      partials[(size_t)(m0 + tid) * ntiles + tn] = red[0][tid] + red[1][tid];
  }
}

__global__ __launch_bounds__(512, 2)
void fused_k(const unsigned short* __restrict__ Pall,
             const unsigned short* __restrict__ w0b,
             const float* __restrict__ b0, const float* __restrict__ cb,
             float* __restrict__ part0, float* __restrict__ g0,
             float* __restrict__ cg, const int* __restrict__ target,
             const unsigned short* __restrict__ w1b, const float* __restrict__ b1,
             const int* __restrict__ idx1, const int* __restrict__ cnt1,
             float* __restrict__ part1, float* __restrict__ g1,
             const unsigned short* __restrict__ w2b, const float* __restrict__ b2,
             const int* __restrict__ idx2, const int* __restrict__ cnt2,
             float* __restrict__ part2, float* __restrict__ g2,
             int nt1, int nt2) {
  __shared__ __align__(16) char UB[132096];
  const int bid = blockIdx.x;
  if (bid < 632) {
    head_body(UB, bid, Pall, w0b, b0, cb, part0, g0, cg, target);
  } else if (bid < 632 + 235) {
    tail_body<256>(UB, bid - 632, Pall + 1024, 1344, w1b, b1, 30000, nt1,
                   idx1, cnt1, part1, g1, target, 20000);
  } else {
    tail_body<64>(UB, bid - 867, Pall + 1280, 1344, w2b, b2, 50000, nt2,
                  idx2, cnt2, part2, g2, target, 50000);
  }
}

// ---------------- combine: wave per token ----------------
__global__ __launch_bounds__(256)
void combine_k(const float* __restrict__ part0,
               const float* __restrict__ part1, int nt1,
               const float* __restrict__ part2, int nt2,
               const float* __restrict__ g0, const float* __restrict__ g1,
               const float* __restrict__ g2, const float* __restrict__ cg,
               const int* __restrict__ pos1, const int* __restrict__ pos2,
               const int* __restrict__ target, float* __restrict__ out) {
  const int w = threadIdx.x >> 6, lane = threadIdx.x & 63;
  const int token = blockIdx.x * 4 + w;
  const int t = target[token];

  float S = 0.f;
  for (int i = lane; i < 79; i += 64)
    S += part0[(size_t)token * 79 + i];
#pragma unroll
  for (int off = 1; off < 64; off <<= 1)
    S += __shfl_xor(S, off, 64);
  const float lse_head = __logf(S);

  float res;
  if (t < 20000) {
    res = lse_head - g0[token];
  } else {
    const float* pt; int nt; float gv, ch; int row;
    if (t < 50000) { pt = part1; nt = nt1; gv = g1[token]; ch = cg[2 * token + 1]; row = pos1[token]; }
    else           { pt = part2; nt = nt2; gv = g2[token]; ch = cg[2 * token];     row = pos2[token]; }
    float S2 = 0.f;
    for (int i = lane; i < nt; i += 64)
      S2 += pt[(size_t)row * nt + i];
#pragma unroll
    for (int off = 1; off < 64; off <<= 1)
      S2 += __shfl_xor(S2, off, 64);
    float lse_t = __logf(S2);
    res = -((ch - lse_head) + (gv - lse_t));
  }
  if (lane == 0) out[token] = res;
}

extern "C" void kernel_launch(void* const* d_in, const int* in_sizes, int n_in,
                              void* d_out, int out_size, void* d_ws, size_t ws_size,
                              hipStream_t stream) {
  (void)in_sizes; (void)n_in; (void)out_size; (void)ws_size;
  const float* hidden = (const float*)d_in[0];
  const int*   target = (const int*)d_in[1];
  const float* w0     = (const float*)d_in[2];
  const float* b0     = (const float*)d_in[3];
  const float* cw     = (const float*)d_in[4];
  const float* cb     = (const float*)d_in[5];
  const float* proj0  = (const float*)d_in[6];
  const float* w1     = (const float*)d_in[7];
  const float* b1     = (const float*)d_in[8];
  const float* proj1  = (const float*)d_in[9];
  const float* w2     = (const float*)d_in[10];
  const float* b2     = (const float*)d_in[11];
  const float* proj2  = (const float*)d_in[12];
  float* out = (float*)d_out;

  const int NT1 = 235, NT2 = 391;

  char* p = (char*)d_ws;
  auto alloc = [&](size_t bytes) {
    char* r = p; p += (bytes + 255) & ~(size_t)255; return r;
  };
  unsigned short* Hb   = (unsigned short*)alloc(2048ull * 1024 * 2);
  unsigned short* pAll = (unsigned short*)alloc(1344ull * 1024 * 2);
  unsigned short* w0b  = (unsigned short*)alloc(20002ull * 1024 * 2);
  unsigned short* w1b  = (unsigned short*)alloc(30000ull * 256 * 2);
  unsigned short* w2b  = (unsigned short*)alloc(50000ull * 64 * 2);
  unsigned short* Pall = (unsigned short*)alloc(2048ull * 1344 * 2);
  float* part0 = (float*)alloc(2048ull * 79 * 4);
  float* part1 = (float*)alloc(2048ull * NT1 * 4);
  float* part2 = (float*)alloc(2048ull * NT2 * 4);
  float* g0 = (float*)alloc(2048 * 4);
  float* g1 = (float*)alloc(2048 * 4);
  float* g2 = (float*)alloc(2048 * 4);
  float* cg = (float*)alloc(2048 * 2 * 4);
  int* idx1 = (int*)alloc(2048 * 4);
  int* pos1 = (int*)alloc(2048 * 4);
  int* idx2 = (int*)alloc(2048 * 4);
  int* pos2 = (int*)alloc(2048 * 4);
  int* cnts = (int*)alloc(2 * 4);

  const int c_h = 2048 * 1024 / 4, c_w0 = 20000 * 1024 / 4, c_cw = 2048 / 4,
            c_w1 = 30000 * 256 / 4, c_w2 = 50000 * 64 / 4;
  const int ctot = c_h + c_w0 + c_cw + c_w1 + c_w2;
  const int nb_cast = (ctot + 255) / 256;
  prep_k<<<1 + 1344 + nb_cast, 256, 0, stream>>>(
      target, idx1, pos1, idx2, pos2, cnts,
      proj0, proj1, proj2, pAll,
      hidden, Hb, c_h,
      w0, w0b, c_w0,
      cw, w0b + 20000ull * 1024, c_cw,
      w1, w1b, c_w1,
      w2, w2b, c_w2);

  // merged projections: Pall[2048,1344] = Hb @ pAll^T
  proj_gemm_k<<<dim3(16, 11), 256, 0, stream>>>(Hb, pAll, Pall);

  // fused head + tails: 632 head tiles, then 235 + 391 tail stripes
  fused_k<<<632 + NT1 + NT2, 512, 0, stream>>>(
      Pall, w0b, b0, cb, part0, g0, cg, target,
      w1b, b1, idx1, cnts + 0, part1, g1,
      w2b, b2, idx2, cnts + 1, part2, g2,
      NT1, NT2);

  combine_k<<<512, 256, 0, stream>>>(part0, part1, NT1, part2, NT2,
      g0, g1, g2, cg, pos1, pos2, target, out);
}

// Round 7
// 384.250 us; speedup vs baseline: 1.1312x; 1.0887x over previous
//
#include <hip/hip_runtime.h>
#include <cstdint>
#include <cstddef>

#define DEV static __device__ __forceinline__

typedef __attribute__((ext_vector_type(8))) short bf16x8_t;
typedef __attribute__((ext_vector_type(4))) float f32x4_t;

DEV unsigned short f2bf(float f) {
  union { float f; unsigned u; } v; v.f = f;
  unsigned r = v.u + 0x7fffu + ((v.u >> 16) & 1u);
  return (unsigned short)(r >> 16);
}

// async global->LDS, 16B per lane; LDS dest = WAVE-UNIFORM base + lane*16
DEV void gl_lds16(const void* g, void* l) {
  __builtin_amdgcn_global_load_lds(
      (const __attribute__((address_space(1))) void*)g,
      (__attribute__((address_space(3))) void*)l,
      16, 0, 0);
}

// ---------------- prep: build_idx + casts + transposes, one launch --------
__global__ __launch_bounds__(256)
void prep_k(const int* __restrict__ target,
            int* __restrict__ idx1, int* __restrict__ pos1,
            int* __restrict__ idx2, int* __restrict__ pos2,
            int* __restrict__ cnts,
            const float* __restrict__ p0, const float* __restrict__ p1,
            const float* __restrict__ p2, unsigned short* __restrict__ pAll,
            const float* __restrict__ s0, unsigned short* __restrict__ d0, int n0,
            const float* __restrict__ s1, unsigned short* __restrict__ d1, int n1,
            const float* __restrict__ s2, unsigned short* __restrict__ d2, int n2,
            const float* __restrict__ s3, unsigned short* __restrict__ d3, int n3,
            const float* __restrict__ s4, unsigned short* __restrict__ d4, int n4) {
  const int bid = blockIdx.x;
  const int tid = threadIdx.x;
  if (bid == 0) {
    __shared__ int c1, c2;
    if (tid == 0) { c1 = 0; c2 = 0; }
    __syncthreads();
    for (int i = tid; i < 2048; i += 256) {
      int t = target[i];
      if (t >= 20000 && t < 50000) {
        int p = atomicAdd(&c1, 1); idx1[p] = i; pos1[i] = p;
      } else if (t >= 50000) {
        int p = atomicAdd(&c2, 1); idx2[p] = i; pos2[i] = p;
      }
    }
    __syncthreads();
    if (tid == 0) { cnts[0] = c1; cnts[1] = c2; }
    return;
  }
  if (bid <= 1344) {
    __shared__ float tile[32][33];
    int b = bid - 1;
    const float* src; unsigned short* dst; int C, bx, by;
    if (b < 1024)      { src = p0; dst = pAll;               C = 1024; bx = b % 32; by = b / 32; }
    else if (b < 1280) { int q = b - 1024; src = p1; dst = pAll + 1024 * 1024; C = 256; bx = q % 8; by = q / 8; }
    else               { int q = b - 1280; src = p2; dst = pAll + 1280 * 1024; C = 64;  bx = q % 2; by = q / 2; }
    const int R = 1024;
    int tx = tid & 31, ty = tid >> 5;
    int c0 = bx * 32, r0 = by * 32;
    for (int yy = ty; yy < 32; yy += 8)
      tile[yy][tx] = src[(size_t)(r0 + yy) * C + (c0 + tx)];
    __syncthreads();
    for (int yy = ty; yy < 32; yy += 8)
      dst[(size_t)(c0 + yy) * R + (r0 + tx)] = f2bf(tile[tx][yy]);
    return;
  }
  int j = (bid - 1345) * 256 + tid;
  const float* s; unsigned short* d;
  if (j < n0) { s = s0; d = d0; }
  else { j -= n0;
    if (j < n1) { s = s1; d = d1; }
    else { j -= n1;
      if (j < n2) { s = s2; d = d2; }
      else { j -= n2;
        if (j < n3) { s = s3; d = d3; }
        else { j -= n3; if (j >= n4) return; s = s4; d = d4; }
      }
    }
  }
  float4 f = ((const float4*)s)[j];
  ushort4 o;
  o.x = f2bf(f.x); o.y = f2bf(f.y); o.z = f2bf(f.z); o.w = f2bf(f.w);
  ((ushort4*)d)[j] = o;
}

// ---------------- proj GEMM: Pall[2048,1344] = Hb @ pAll^T ----------------
__global__ __launch_bounds__(256)
void proj_gemm_k(const unsigned short* __restrict__ A,
                 const unsigned short* __restrict__ W,
                 unsigned short* __restrict__ Cout) {
  __shared__ __align__(16) unsigned short As[128 * 32];
  __shared__ __align__(16) unsigned short Bs[128 * 32];
  const int K = 1024, V = 1344;
  const int tm = blockIdx.x, tn = blockIdx.y;
  const int m0 = tm * 128, n0 = tn * 128;
  const int tid = threadIdx.x, wid = tid >> 6, lane = tid & 63;
  const int quad = lane >> 4, l16 = lane & 15;
  const int wr = wid >> 1, wc = wid & 1;

  f32x4_t acc[4][4];
  const f32x4_t zero4 = {0.f, 0.f, 0.f, 0.f};
#pragma unroll
  for (int i = 0; i < 4; ++i)
#pragma unroll
    for (int j = 0; j < 4; ++j) acc[i][j] = zero4;

  const int srow = wid * 32 + (lane >> 2);
  const int skk  = (lane & 3) * 8;
  const unsigned short* Ap0 = A + (size_t)(m0 + srow) * K + skk;
  const unsigned short* Ap1 = A + (size_t)(m0 + srow + 16) * K + skk;
  int wrow0 = n0 + srow;      if (wrow0 > V - 1) wrow0 = V - 1;
  int wrow1 = n0 + srow + 16; if (wrow1 > V - 1) wrow1 = V - 1;
  const unsigned short* Wp0 = W + (size_t)wrow0 * K + skk;
  const unsigned short* Wp1 = W + (size_t)wrow1 * K + skk;
  unsigned short* Asw = As + wid * 1024;
  unsigned short* Bsw = Bs + wid * 1024;

  for (int k0 = 0; k0 < K; k0 += 32) {
    gl_lds16(Ap0, Asw);
    gl_lds16(Ap1, Asw + 512);
    gl_lds16(Wp0, Bsw);
    gl_lds16(Wp1, Bsw + 512);
    Ap0 += 32; Ap1 += 32; Wp0 += 32; Wp1 += 32;
    __syncthreads();
    bf16x8_t af[4], bfr[4];
#pragma unroll
    for (int i = 0; i < 4; ++i)
      af[i] = *(const bf16x8_t*)(As + (size_t)(wr * 64 + i * 16 + l16) * 32 + quad * 8);
#pragma unroll
    for (int j = 0; j < 4; ++j)
      bfr[j] = *(const bf16x8_t*)(Bs + (size_t)(wc * 64 + j * 16 + l16) * 32 + quad * 8);
#pragma unroll
    for (int i = 0; i < 4; ++i)
#pragma unroll
      for (int j = 0; j < 4; ++j)
        acc[i][j] = __builtin_amdgcn_mfma_f32_16x16x32_bf16(af[i], bfr[j], acc[i][j], 0, 0, 0);
    __syncthreads();
  }
#pragma unroll
  for (int i = 0; i < 4; ++i)
#pragma unroll
    for (int j = 0; j < 4; ++j) {
      const int n = n0 + wc * 64 + j * 16 + l16;
      if (n < V) {
#pragma unroll
        for (int r = 0; r < 4; ++r) {
          const int m = m0 + wr * 64 + i * 16 + quad * 4 + r;
          Cout[(size_t)m * V + n] = f2bf(acc[i][j][r]);
        }
      }
    }
}

// ================= fused head + tails (one launch, 512 thr) ===============
// bids [0,632): head 256x256 pipelined GEMM (byte-identical R4 schedule).
// bids [632,867): tail1 stripes (KT=256).  [867,1258): tail2 (KT=64).
// R7 = R6 with de-risk fixes: ALL tail gl_lds16 LDS destinations are
// wave-uniform bases (+ wid*1024; HW adds lane*16 -> identical layout to
// R6's intended + tid*16, which violated the wave-uniform contract and is
// the prime suspect for the R6 container hang); ar clamped >= 0.

#define SBAR() __builtin_amdgcn_s_barrier()

#define STA(BUF, HALF, KT)                                                    \
  {                                                                           \
    const unsigned short* g_ = aB0 + (size_t)(HALF) * (128 * 1344) + (KT) * 64; \
    char* d_ = (char*)SA[BUF][HALF] + ldsw;                                   \
    gl_lds16(g_, d_);                                                         \
    gl_lds16(g_ + 64 * 1344, d_ + 8192);                                      \
  }

#define STB(BUF, HALF, KT)                                                    \
  {                                                                           \
    char* d_ = (char*)SB[BUF][HALF] + ldsw;                                   \
    gl_lds16(bP##HALF##0 + (KT) * 64, d_);                                    \
    gl_lds16(bP##HALF##1 + (KT) * 64, d_ + 8192);                             \
  }

#define MMQ(mb, nb, BB)                                                       \
  {                                                                           \
    _Pragma("unroll") for (int mi = 0; mi < 4; ++mi) {                        \
      _Pragma("unroll") for (int nj = 0; nj < 2; ++nj) {                      \
        acc[(mb) + mi][(nb) + nj] = __builtin_amdgcn_mfma_f32_16x16x32_bf16(  \
            Af[0][mi], BB[0][nj], acc[(mb) + mi][(nb) + nj], 0, 0, 0);        \
        acc[(mb) + mi][(nb) + nj] = __builtin_amdgcn_mfma_f32_16x16x32_bf16(  \
            Af[1][mi], BB[1][nj], acc[(mb) + mi][(nb) + nj], 0, 0, 0);        \
      }                                                                       \
    }                                                                         \
  }

#define PH(D_, E_, KTV)                                                       \
  {                                                                           \
    const int kt_ = (KTV);                                                    \
    const int t1_ = (kt_ + 1 > 15) ? 15 : (kt_ + 1);                          \
    const int t2_ = (kt_ + 2 > 15) ? 15 : (kt_ + 2);                          \
    /* W0: Af-lo (same-window) + Bh (for W1); stage B[E].h1(kt+1) */          \
    _Pragma("unroll") for (int mi = 0; mi < 4; ++mi) {                        \
      Af[0][mi] = *(const bf16x8_t*)(pa##D_##a + mi * 2048);                  \
      Af[1][mi] = *(const bf16x8_t*)(pa##D_##b + mi * 2048);                  \
    }                                                                         \
    _Pragma("unroll") for (int nj = 0; nj < 2; ++nj) {                        \
      Bh[0][nj] = *(const bf16x8_t*)(pb##D_##a + (2 + nj) * 2048);            \
      Bh[1][nj] = *(const bf16x8_t*)(pb##D_##b + (2 + nj) * 2048);            \
    }                                                                         \
    STB(E_, 1, t1_);                                                          \
    __builtin_amdgcn_s_setprio(1); MMQ(0, 0, Bl); __builtin_amdgcn_s_setprio(0); \
    SBAR();                                                                   \
    /* W1: MFMA lo x Bh; then Af-hi (for W2); stage A[E].h1(kt+1) */          \
    __builtin_amdgcn_s_setprio(1); MMQ(0, 2, Bh); __builtin_amdgcn_s_setprio(0); \
    _Pragma("unroll") for (int mi = 0; mi < 4; ++mi) {                        \
      Af[0][mi] = *(const bf16x8_t*)(pa##D_##a + (4 + mi) * 2048);            \
      Af[1][mi] = *(const bf16x8_t*)(pa##D_##b + (4 + mi) * 2048);            \
    }                                                                         \
    STA(E_, 1, t1_);                                                          \
    SBAR();                                                                   \
    /* W2: stage B[D].h0(kt+2); MFMA hi x Bl; counted vmcnt gate */           \
    STB(D_, 0, t2_);                                                          \
    __builtin_amdgcn_s_setprio(1); MMQ(4, 0, Bl); __builtin_amdgcn_s_setprio(0); \
    asm volatile("s_waitcnt vmcnt(2)" ::: "memory");                          \
    SBAR();                                                                   \
    /* W3: stage A[D].h0(kt+2); Bl(next) (for next W0); MFMA hi x Bh */       \
    STA(D_, 0, t2_);                                                          \
    _Pragma("unroll") for (int nj = 0; nj < 2; ++nj) {                        \
      Bl[0][nj] = *(const bf16x8_t*)(pb##E_##a + nj * 2048);                  \
      Bl[1][nj] = *(const bf16x8_t*)(pb##E_##b + nj * 2048);                  \
    }                                                                         \
    __builtin_amdgcn_s_setprio(1); MMQ(4, 2, Bh); __builtin_amdgcn_s_setprio(0); \
    SBAR();                                                                   \
  }

#define PROLOGUE6()                                                           \
  { STB(0, 0, 0); STA(0, 0, 0); STB(0, 1, 0); STA(0, 1, 0);                   \
    STB(1, 0, 1); STA(1, 0, 1); }

typedef unsigned short lds_half_t[2][8192];

DEV void head_body(char* UB, int bid,
                   const unsigned short* __restrict__ Pall,
                   const unsigned short* __restrict__ w0b,
                   const float* __restrict__ b0, const float* __restrict__ cb,
                   float* __restrict__ part0, float* __restrict__ g0,
                   float* __restrict__ cg, const int* __restrict__ target) {
  lds_half_t* SA = (lds_half_t*)UB;              // [2][2][8192] shorts, 64 KB
  lds_half_t* SB = (lds_half_t*)(UB + 65536);    // 64 KB

  const int V = 20002;
  const int orig = (bid & 7) * 79 + (bid >> 3);
  const int mt = orig & 7, stripe = orig >> 3;
  const int m0 = mt * 256, n0 = stripe * 256;

  const int tid = threadIdx.x;
  const int wid = tid >> 6, lane = tid & 63;
  const int quad = lane >> 4, l16 = lane & 15;
  const int wr = wid >> 2, wc = wid & 3;

  const int r0  = tid >> 3;                       // phys row 0..63
  const int ibh = ((tid & 7) ^ (r0 & 7)) << 3;    // logical element col

  const unsigned short* aB0 = Pall + (size_t)(m0 + r0) * 1344 + ibh;
  int br00 = n0 + r0;            if (br00 > V - 1) br00 = V - 1;
  int br01 = n0 + r0 + 64;       if (br01 > V - 1) br01 = V - 1;
  int br10 = n0 + 128 + r0;      if (br10 > V - 1) br10 = V - 1;
  int br11 = n0 + 128 + r0 + 64; if (br11 > V - 1) br11 = V - 1;
  const unsigned short* bP00 = w0b + (size_t)br00 * 1024 + ibh;
  const unsigned short* bP01 = w0b + (size_t)br01 * 1024 + ibh;
  const unsigned short* bP10 = w0b + (size_t)br10 * 1024 + ibh;
  const unsigned short* bP11 = w0b + (size_t)br11 * 1024 + ibh;

  const int ldsw = wid * 1024;  // wave-uniform gl_lds dest base

  const int aoff0 = l16 * 128 + ((quad ^ (l16 & 3)) << 4) + (((l16 >> 2) & 1) << 6);
  const int aoff1 = aoff0 ^ 64;
  const char* pa0a = (const char*)SA[0][wr] + aoff0;
  const char* pa0b = (const char*)SA[0][wr] + aoff1;
  const char* pa1a = (const char*)SA[1][wr] + aoff0;
  const char* pa1b = (const char*)SA[1][wr] + aoff1;
  const char* pb0a = (const char*)SB[0][wc >> 1] + (wc & 1) * 8192 + aoff0;
  const char* pb0b = (const char*)SB[0][wc >> 1] + (wc & 1) * 8192 + aoff1;
  const char* pb1a = (const char*)SB[1][wc >> 1] + (wc & 1) * 8192 + aoff0;
  const char* pb1b = (const char*)SB[1][wc >> 1] + (wc & 1) * 8192 + aoff1;

  f32x4_t acc[8][4];
  const f32x4_t zero4 = {0.f, 0.f, 0.f, 0.f};
#pragma unroll
  for (int i = 0; i < 8; ++i)
#pragma unroll
    for (int j = 0; j < 4; ++j) acc[i][j] = zero4;

  bf16x8_t Af[2][4];
  bf16x8_t Bl[2][2];
  bf16x8_t Bh[2][2];

  PROLOGUE6();
  asm volatile("s_waitcnt vmcnt(4)" ::: "memory");
  SBAR();
#pragma unroll
  for (int nj = 0; nj < 2; ++nj) {
    Bl[0][nj] = *(const bf16x8_t*)(pb0a + nj * 2048);
    Bl[1][nj] = *(const bf16x8_t*)(pb0b + nj * 2048);
  }

#pragma unroll 1
  for (int ktp = 0; ktp < 8; ++ktp) {
    const int kt0 = 2 * ktp;
    PH(0, 1, kt0);
    PH(1, 0, kt0 + 1);
  }

  asm volatile("s_waitcnt vmcnt(0) lgkmcnt(0)" ::: "memory");
  SBAR();

  int nj[4]; float bj[4];
#pragma unroll
  for (int j = 0; j < 4; ++j) {
    nj[j] = n0 + wc * 64 + j * 16 + l16;
    bj[j] = (nj[j] < 20000) ? b0[nj[j]] : ((nj[j] < V) ? cb[nj[j] - 20000] : 0.f);
  }
  float* redf = (float*)UB;  // 8 x 128 floats (aliases SA; drained above)
#pragma unroll
  for (int i = 0; i < 8; ++i) {
#pragma unroll
    for (int r = 0; r < 4; ++r) {
      const int rloc = i * 16 + quad * 4 + r;
      const int token = m0 + wr * 128 + rloc;
      float v[4], sum = 0.f;
#pragma unroll
      for (int j = 0; j < 4; ++j) {
        v[j] = acc[i][j][r] + bj[j];
        if (nj[j] < V) sum += __expf(v[j]);
      }
#pragma unroll
      for (int off = 1; off < 16; off <<= 1)
        sum += __shfl_xor(sum, off, 64);
      if (l16 == 0) redf[(wr * 4 + wc) * 128 + rloc] = sum;
      const int t = target[token];
      const int gi = (t < 19999) ? t : 19999;
#pragma unroll
      for (int j = 0; j < 4; ++j) {
        if (nj[j] == gi) g0[token] = v[j];
        if (nj[j] == 20000) cg[2 * token]     = v[j];
        if (nj[j] == 20001) cg[2 * token + 1] = v[j];
      }
    }
  }
  __syncthreads();
  if (tid < 256) {
    const int wrr = tid >> 7, rr = tid & 127;
    const float s = redf[(wrr * 4 + 0) * 128 + rr] + redf[(wrr * 4 + 1) * 128 + rr]
                  + redf[(wrr * 4 + 2) * 128 + rr] + redf[(wrr * 4 + 3) * 128 + rr];
    part0[(size_t)(m0 + tid) * 79 + stripe] = s;
  }
}

#undef PH
#undef MMQ
#undef STA
#undef STB
#undef PROLOGUE6
#undef SBAR

// ---------------- tail body: 8-wave 256x128 tile, dbuf BK=64 pipeline -----
// Output tile 256 rows (gathered via rowidx) x 128 vocab cols per block.
// Wave grid 4x2: wr=wid>>1 (m-quadrant), wc=wid&1 (n-half); 64x64/wave.
// B-stripe (128 x KT) staged to LDS once. A staged in BK=64 double-buffered
// chunks; stage(s+1) issued BEFORE compute(s) so the end-of-step
// __syncthreads vmcnt-drain lands after MFMA+epilogue covered HBM latency.
// gl_lds16 dests are wave-uniform (+wid*1024); HW adds lane*16 ->
// chunk byte layout [row=tid>>2][col=(tid&3)*8] as designed.
template <int KT>
DEV void tail_body8(char* UB, int tn,
                    const unsigned short* __restrict__ A, int ldA,
                    const unsigned short* __restrict__ W,
                    const float* __restrict__ bias, int V, int nt2x,
                    const int* __restrict__ rowidx,
                    const int* __restrict__ cnt_ptr,
                    float* __restrict__ partials,
                    float* __restrict__ gathered,
                    const int* __restrict__ target, int glo) {
  constexpr int KC  = KT / 64;   // K-steps per m-tile (4 or 1)
  constexpr int NCB = KT / 32;   // B chunks of 32 cols
  unsigned short* Bs = (unsigned short*)UB;        // NCB * 8192 bytes
  char* AsB = UB + NCB * 8192;                     // 2 bufs * 32768 bytes

  const int n0 = tn * 128;
  const int Meff = *cnt_ptr;
  const int tid = threadIdx.x;
  const int lane = tid & 63, wid = tid >> 6;
  const int quad = lane >> 4, l16 = lane & 15;
  const int wr = wid >> 1, wc = wid & 1;
  const int srow = tid >> 2;          // staging row 0..127
  const int scol = (tid & 3) * 8;     // element col within 32-col chunk
  const int ldsw = wid * 1024;        // wave-uniform dest base within chunk

  // stage full B stripe once (linear LDS [128][32] per chunk)
  int wrow = n0 + srow; if (wrow > V - 1) wrow = V - 1;
#pragma unroll
  for (int c = 0; c < NCB; ++c)
    gl_lds16(W + (size_t)wrow * KT + c * 32 + scol, (char*)Bs + c * 8192 + ldsw);

  int nj[4]; float bj[4];
#pragma unroll
  for (int j = 0; j < 4; ++j) {
    nj[j] = n0 + wc * 64 + j * 16 + l16;
    bj[j] = (nj[j] < V) ? bias[nj[j]] : 0.f;
  }

  const int nm = (Meff + 255) >> 8;
  const int S = nm * KC;

  auto stageA = [&](int s, int buf) {
    const int m = s / KC, k = s - m * KC;
#pragma unroll
    for (int cc = 0; cc < 2; ++cc)
#pragma unroll
      for (int h = 0; h < 2; ++h) {
        int ar = m * 256 + srow + h * 128;
        if (ar > Meff - 1) ar = Meff - 1;
        if (ar < 0) ar = 0;
        const int Arow = rowidx[ar];
        gl_lds16(A + (size_t)Arow * ldA + k * 64 + cc * 32 + scol,
                 AsB + buf * 32768 + cc * 16384 + h * 8192 + ldsw);
      }
  };

  stageA(0, 0);
  __syncthreads();  // drains B + A(0)

  f32x4_t acc[4][4];
  const f32x4_t zero4 = {0.f, 0.f, 0.f, 0.f};

  for (int s = 0; s < S; ++s) {
    const int buf = s & 1;
    const int m = s / KC, k = s - m * KC;
    if (s + 1 < S) stageA(s + 1, buf ^ 1);  // in flight under compute
    if (k == 0) {
#pragma unroll
      for (int i = 0; i < 4; ++i)
#pragma unroll
        for (int j = 0; j < 4; ++j) acc[i][j] = zero4;
    }
#pragma unroll
    for (int cc = 0; cc < 2; ++cc) {
      bf16x8_t af[4], bfr[4];
#pragma unroll
      for (int i = 0; i < 4; ++i)
        af[i] = *(const bf16x8_t*)(AsB + buf * 32768 + cc * 16384 +
                                   (wr * 64 + i * 16 + l16) * 64 + quad * 16);
#pragma unroll
      for (int j = 0; j < 4; ++j)
        bfr[j] = *(const bf16x8_t*)((char*)Bs + (k * 2 + cc) * 8192 +
                                    (wc * 64 + j * 16 + l16) * 64 + quad * 16);
#pragma unroll
      for (int i = 0; i < 4; ++i)
#pragma unroll
        for (int j = 0; j < 4; ++j)
          acc[i][j] = __builtin_amdgcn_mfma_f32_16x16x32_bf16(af[i], bfr[j], acc[i][j], 0, 0, 0);
    }
    if (k == KC - 1) {
      // epilogue for m-tile (registers + global only; no LDS)
#pragma unroll
      for (int i = 0; i < 4; ++i) {
#pragma unroll
        for (int r = 0; r < 4; ++r) {
          const int row = wr * 64 + i * 16 + quad * 4 + r;  // 0..255
          const int gr = m * 256 + row;
          const int grc = (gr < Meff) ? gr : (Meff - 1);
          const int token = rowidx[grc];
          float v[4], sum = 0.f;
#pragma unroll
          for (int j = 0; j < 4; ++j) {
            v[j] = acc[i][j][r] + bj[j];
            if (nj[j] < V) sum += __expf(v[j]);
          }
#pragma unroll
          for (int off = 1; off < 16; off <<= 1)
            sum += __shfl_xor(sum, off, 64);
          if (l16 == 0)
            partials[(size_t)grc * nt2x + 2 * tn + wc] = sum;
          const int gi = target[token] - glo;
#pragma unroll
          for (int j = 0; j < 4; ++j)
            if (nj[j] == gi) gathered[token] = v[j];
        }
      }
    }
    __syncthreads();  // drains stage(s+1); WAR-fences A[buf] for s+2
  }
}

__global__ __launch_bounds__(512, 2)
void fused_k(const unsigned short* __restrict__ Pall,
             const unsigned short* __restrict__ w0b,
             const float* __restrict__ b0, const float* __restrict__ cb,
             float* __restrict__ part0, float* __restrict__ g0,
             float* __restrict__ cg, const int* __restrict__ target,
             const unsigned short* __restrict__ w1b, const float* __restrict__ b1,
             const int* __restrict__ idx1, const int* __restrict__ cnt1,
             float* __restrict__ part1, float* __restrict__ g1,
             const unsigned short* __restrict__ w2b, const float* __restrict__ b2,
             const int* __restrict__ idx2, const int* __restrict__ cnt2,
             float* __restrict__ part2, float* __restrict__ g2,
             int nt1x2, int nt2x2) {
  __shared__ __align__(16) char UB[132096];
  const int bid = blockIdx.x;
  if (bid < 632) {
    head_body(UB, bid, Pall, w0b, b0, cb, part0, g0, cg, target);
  } else if (bid < 632 + 235) {
    tail_body8<256>(UB, bid - 632, Pall + 1024, 1344, w1b, b1, 30000, nt1x2,
                    idx1, cnt1, part1, g1, target, 20000);
  } else {
    tail_body8<64>(UB, bid - 867, Pall + 1280, 1344, w2b, b2, 50000, nt2x2,
                   idx2, cnt2, part2, g2, target, 50000);
  }
}

// ---------------- combine: wave per token ----------------
__global__ __launch_bounds__(256)
void combine_k(const float* __restrict__ part0,
               const float* __restrict__ part1, int nt1,
               const float* __restrict__ part2, int nt2,
               const float* __restrict__ g0, const float* __restrict__ g1,
               const float* __restrict__ g2, const float* __restrict__ cg,
               const int* __restrict__ pos1, const int* __restrict__ pos2,
               const int* __restrict__ target, float* __restrict__ out) {
  const int w = threadIdx.x >> 6, lane = threadIdx.x & 63;
  const int token = blockIdx.x * 4 + w;
  const int t = target[token];

  float S = 0.f;
  for (int i = lane; i < 79; i += 64)
    S += part0[(size_t)token * 79 + i];
#pragma unroll
  for (int off = 1; off < 64; off <<= 1)
    S += __shfl_xor(S, off, 64);
  const float lse_head = __logf(S);

  float res;
  if (t < 20000) {
    res = lse_head - g0[token];
  } else {
    const float* pt; int nt; float gv, ch; int row;
    if (t < 50000) { pt = part1; nt = nt1; gv = g1[token]; ch = cg[2 * token + 1]; row = pos1[token]; }
    else           { pt = part2; nt = nt2; gv = g2[token]; ch = cg[2 * token];     row = pos2[token]; }
    float S2 = 0.f;
    for (int i = lane; i < nt; i += 64)
      S2 += pt[(size_t)row * nt + i];
#pragma unroll
    for (int off = 1; off < 64; off <<= 1)
      S2 += __shfl_xor(S2, off, 64);
    float lse_t = __logf(S2);
    res = -((ch - lse_head) + (gv - lse_t));
  }
  if (lane == 0) out[token] = res;
}

extern "C" void kernel_launch(void* const* d_in, const int* in_sizes, int n_in,
                              void* d_out, int out_size, void* d_ws, size_t ws_size,
                              hipStream_t stream) {
  (void)in_sizes; (void)n_in; (void)out_size; (void)ws_size;
  const float* hidden = (const float*)d_in[0];
  const int*   target = (const int*)d_in[1];
  const float* w0     = (const float*)d_in[2];
  const float* b0     = (const float*)d_in[3];
  const float* cw     = (const float*)d_in[4];
  const float* cb     = (const float*)d_in[5];
  const float* proj0  = (const float*)d_in[6];
  const float* w1     = (const float*)d_in[7];
  const float* b1     = (const float*)d_in[8];
  const float* proj1  = (const float*)d_in[9];
  const float* w2     = (const float*)d_in[10];
  const float* b2     = (const float*)d_in[11];
  const float* proj2  = (const float*)d_in[12];
  float* out = (float*)d_out;

  const int NT1 = 235, NT2 = 391;
  const int NT1X = 2 * NT1, NT2X = 2 * NT2;  // per-wc partial columns

  char* p = (char*)d_ws;
  auto alloc = [&](size_t bytes) {
    char* r = p; p += (bytes + 255) & ~(size_t)255; return r;
  };
  unsigned short* Hb   = (unsigned short*)alloc(2048ull * 1024 * 2);
  unsigned short* pAll = (unsigned short*)alloc(1344ull * 1024 * 2);
  unsigned short* w0b  = (unsigned short*)alloc(20002ull * 1024 * 2);
  unsigned short* w1b  = (unsigned short*)alloc(30000ull * 256 * 2);
  unsigned short* w2b  = (unsigned short*)alloc(50000ull * 64 * 2);
  unsigned short* Pall = (unsigned short*)alloc(2048ull * 1344 * 2);
  float* part0 = (float*)alloc(2048ull * 79 * 4);
  float* part1 = (float*)alloc(2048ull * NT1X * 4);
  float* part2 = (float*)alloc(2048ull * NT2X * 4);
  float* g0 = (float*)alloc(2048 * 4);
  float* g1 = (float*)alloc(2048 * 4);
  float* g2 = (float*)alloc(2048 * 4);
  float* cg = (float*)alloc(2048 * 2 * 4);
  int* idx1 = (int*)alloc(2048 * 4);
  int* pos1 = (int*)alloc(2048 * 4);
  int* idx2 = (int*)alloc(2048 * 4);
  int* pos2 = (int*)alloc(2048 * 4);
  int* cnts = (int*)alloc(2 * 4);

  const int c_h = 2048 * 1024 / 4, c_w0 = 20000 * 1024 / 4, c_cw = 2048 / 4,
            c_w1 = 30000 * 256 / 4, c_w2 = 50000 * 64 / 4;
  const int ctot = c_h + c_w0 + c_cw + c_w1 + c_w2;
  const int nb_cast = (ctot + 255) / 256;
  prep_k<<<1 + 1344 + nb_cast, 256, 0, stream>>>(
      target, idx1, pos1, idx2, pos2, cnts,
      proj0, proj1, proj2, pAll,
      hidden, Hb, c_h,
      w0, w0b, c_w0,
      cw, w0b + 20000ull * 1024, c_cw,
      w1, w1b, c_w1,
      w2, w2b, c_w2);

  // merged projections: Pall[2048,1344] = Hb @ pAll^T
  proj_gemm_k<<<dim3(16, 11), 256, 0, stream>>>(Hb, pAll, Pall);

  // fused head + tails: 632 head tiles, then 235 + 391 tail stripes
  fused_k<<<632 + NT1 + NT2, 512, 0, stream>>>(
      Pall, w0b, b0, cb, part0, g0, cg, target,
      w1b, b1, idx1, cnts + 0, part1, g1,
      w2b, b2, idx2, cnts + 1, part2, g2,
      NT1X, NT2X);

  combine_k<<<512, 256, 0, stream>>>(part0, part1, NT1X, part2, NT2X,
      g0, g1, g2, cg, pos1, pos2, target, out);
}